// Round 4
// baseline (1127.730 us; speedup 1.0000x reference)
//
#include <hip/hip_runtime.h>
#include <hip/hip_bf16.h>

// ---- JAX PRNG variant switches (verified passing in R2) ----
#define JAX_PARTITIONABLE 1
#define PART_MODE 2   // bits = o0 ^ o1

#define HW 4096      // 64*64 pixels
#define NS 12        // num_steps
#define PPB 49152    // HW*NS points per batch element

__host__ __device__ __forceinline__ void tf2x32(unsigned k0, unsigned k1,
                                                unsigned x0, unsigned x1,
                                                unsigned &o0, unsigned &o1) {
  unsigned ks2 = k0 ^ k1 ^ 0x1BD11BDAu;
  unsigned v0 = x0 + k0, v1 = x1 + k1;
#define TFR(r) do { v0 += v1; v1 = (v1 << (r)) | (v1 >> (32 - (r))); v1 ^= v0; } while (0)
  TFR(13); TFR(15); TFR(26); TFR(6);   v0 += k1;  v1 += ks2 + 1u;
  TFR(17); TFR(29); TFR(16); TFR(24);  v0 += ks2; v1 += k0 + 2u;
  TFR(13); TFR(15); TFR(26); TFR(6);   v0 += k0;  v1 += k1 + 3u;
  TFR(17); TFR(29); TFR(16); TFR(24);  v0 += k1;  v1 += ks2 + 4u;
  TFR(13); TFR(15); TFR(26); TFR(6);   v0 += ks2; v1 += k0 + 5u;
#undef TFR
  o0 = v0; o1 = v1;
}

__device__ __forceinline__ float jax_uniform(unsigned k0, unsigned k1,
                                             unsigned idx, unsigned total) {
  unsigned o0, o1, bits;
#if JAX_PARTITIONABLE
  tf2x32(k0, k1, 0u, idx, o0, o1);
#if PART_MODE == 0
  bits = o0;
#elif PART_MODE == 1
  bits = o1;
#else
  bits = o0 ^ o1;
#endif
#else
  unsigned half = total >> 1;
  if (idx < half) { tf2x32(k0, k1, idx, idx + half, o0, o1); bits = o0; }
  else            { tf2x32(k0, k1, idx - half, idx, o0, o1); bits = o1; }
#endif
  return __uint_as_float(0x3f800000u | (bits >> 9)) - 1.0f;
}

__device__ __forceinline__ void pixel_dir(int n, float &dx, float &dy, float &dz) {
  int pi = n >> 6, pj = n & 63;
  float x = -1.0f + (float)pj * (2.0f / 63.0f);
  float y =  1.0f - (float)pi * (2.0f / 63.0f);
  float zc = -1.0f / tanf(0.10471975511965978f);  // deg2rad(12)/2
  float inv = 1.0f / sqrtf(x * x + y * y + zc * zc);
  dx = x * inv; dy = y * inv; dz = zc * inv;
}

// ---------------- mapping network: z(256) -> freqs/phases (768 each) ---------
__global__ __launch_bounds__(256) void k_map(const float *z, const float *w0, const float *b0,
                                             const float *w1, const float *b1,
                                             const float *w2, const float *b2,
                                             float *freqs, float *phases) {
  __shared__ float zl[256], h1[256], h2[256];
  int b = blockIdx.x, t = threadIdx.x;
  zl[t] = z[b * 256 + t];
  __syncthreads();
  float acc = b0[t];
  for (int k = 0; k < 256; k++) acc += zl[k] * w0[k * 256 + t];
  h1[t] = (acc >= 0.0f) ? acc : 0.2f * acc;
  __syncthreads();
  acc = b1[t];
  for (int k = 0; k < 256; k++) acc += h1[k] * w1[k * 256 + t];
  h2[t] = (acc >= 0.0f) ? acc : 0.2f * acc;
  __syncthreads();
  float a6[6];
#pragma unroll
  for (int m = 0; m < 6; m++) a6[m] = b2[t + m * 256];
  for (int k = 0; k < 256; k++) {
    float h = h2[k];
#pragma unroll
    for (int m = 0; m < 6; m++) a6[m] += h * w2[k * 1536 + t + m * 256];
  }
#pragma unroll
  for (int m = 0; m < 6; m++) {
    int o = t + m * 256;
    if (o < 768) freqs[b * 768 + o] = a6[m] * 15.0f + 30.0f;
    else         phases[b * 768 + (o - 768)] = a6[m];
  }
}

// ---------------- coarse rays: perturbed z + transformed points --------------
__global__ __launch_bounds__(256) void k_rays(const float *c2w, float *zv, float *pts,
                                              unsigned kp0, unsigned kp1, int npts) {
  int e = blockIdx.x * 256 + threadIdx.x;
  if (e >= npts) return;
  int b = e / PPB, r = e % PPB, n = r / NS, s = r % NS;
  float dx, dy, dz; pixel_dir(n, dx, dy, dz);
  float delta = (1.12f - 0.88f) / 11.0f;
  float u = jax_uniform(kp0, kp1, (unsigned)e, (unsigned)npts);
  float zval = 0.88f + (float)s * delta + (u - 0.5f) * (float)(0.24 / 11.0);
  zv[e] = zval;
  float px = dx * zval, py = dy * zval, pz = dz * zval;
  const float *M = c2w + b * 16;
  float m[12];
#pragma unroll
  for (int i = 0; i < 12; i++) m[i] = M[i];
  pts[e * 3 + 0] = m[0] * px + m[1] * py + m[2] * pz + m[3];
  pts[e * 3 + 1] = m[4] * px + m[5] * py + m[6] * pz + m[7];
  pts[e * 3 + 2] = m[8] * px + m[9] * py + m[10] * pz + m[11];
}

// ---------------- SIREN forward v3 -------------------------------------------
// Block: 128 threads (2 waves), 64 points, 128 dims. Thread (g=t&15, h=t>>4)
// owns dims {8g..8g+7} x points {8h..8h+7}: per k-step 2 global dwordx4 weight
// loads + 2 ds_read_b128 + 64 FMA -> 0.25 B-LDS/FLOP, VALU-bound (v2 was 0.5,
// LDS-bound at measured 85 B/cyc/CU). xl[128][64]=32KB; XOR swizzle
// col = p ^ (((row>>2)&7)<<2): 16B-aligned, 0 conflicts (verified R3).
__global__ __launch_bounds__(128) void k_siren(const float *pts, const float *freqs,
                                               const float *phases,
                                               const float *fw, const float *fb,
                                               const float *hw, const float *hb,
                                               const float *ow, const float *ob,
                                               float *outp) {
  __shared__ __align__(16) float xl[128 * 64];
  const int t = threadIdx.x;
  const int g = t & 15;        // dim group: dims 8g..8g+7
  const int h = t >> 4;        // point group: points 8h..8h+7
  const int base = blockIdx.x * 64;
  const int b = base / PPB;

  const float *fqb = freqs + b * 768;
  const float *phb = phases + b * 768;

  // ---- first layer: sin(freq * (pts @ fw + fb) + phase) ----
  {
    float pt[24];
    const float4 *ps = (const float4 *)(pts + (size_t)(base + 8 * h) * 3);
#pragma unroll
    for (int i = 0; i < 6; i++) ((float4 *)pt)[i] = ps[i];
    float fqv[8], phv[8], w0v[8], w1v[8], w2v[8], biv[8];
#pragma unroll
    for (int u = 0; u < 2; u++) {
      ((float4 *)fqv)[u] = ((const float4 *)fqb)[2 * g + u];
      ((float4 *)phv)[u] = ((const float4 *)phb)[2 * g + u];
      ((float4 *)w0v)[u] = ((const float4 *)fw)[2 * g + u];
      ((float4 *)w1v)[u] = ((const float4 *)(fw + 128))[2 * g + u];
      ((float4 *)w2v)[u] = ((const float4 *)(fw + 256))[2 * g + u];
      ((float4 *)biv)[u] = ((const float4 *)fb)[2 * g + u];
    }
#pragma unroll
    for (int j = 0; j < 8; j++) {
      float4 v0, v1;
      float *o0 = &v0.x, *o1 = &v1.x;
#pragma unroll
      for (int p = 0; p < 8; p++) {
        float x = pt[3 * p], y = pt[3 * p + 1], z = pt[3 * p + 2];
        float s = sinf(fqv[j] * (x * w0v[j] + y * w1v[j] + z * w2v[j] + biv[j]) + phv[j]);
        if (p < 4) o0[p] = s; else o1[p - 4] = s;
      }
      int r = 8 * g + j;
      int swz = ((r >> 2) & 7) << 2;
      *((float4 *)&xl[r * 64 + ((8 * h) ^ swz)]) = v0;
      *((float4 *)&xl[r * 64 + ((8 * h + 4) ^ swz)]) = v1;
    }
  }
  __syncthreads();

  // ---- hidden layers ----
#pragma unroll 1
  for (int L = 1; L < 6; L++) {
    float fqv[8], phv[8], biv[8];
#pragma unroll
    for (int u = 0; u < 2; u++) {
      ((float4 *)fqv)[u] = ((const float4 *)(fqb + L * 128))[2 * g + u];
      ((float4 *)phv)[u] = ((const float4 *)(phb + L * 128))[2 * g + u];
      ((float4 *)biv)[u] = ((const float4 *)(hb + (L - 1) * 128))[2 * g + u];
    }
    const float4 *Wl = (const float4 *)(hw + (size_t)(L - 1) * 16384);
    float acc[8][8];
#pragma unroll
    for (int j = 0; j < 8; j++)
#pragma unroll
      for (int p = 0; p < 8; p++) acc[j][p] = biv[j];
#pragma unroll 4
    for (int k = 0; k < 128; k++) {
      float4 wa = Wl[k * 32 + 2 * g];
      float4 wb = Wl[k * 32 + 2 * g + 1];
      int swz = ((k >> 2) & 7) << 2;
      float4 x0 = *((const float4 *)&xl[k * 64 + ((8 * h) ^ swz)]);
      float4 x1 = *((const float4 *)&xl[k * 64 + ((8 * h + 4) ^ swz)]);
      float wv[8] = {wa.x, wa.y, wa.z, wa.w, wb.x, wb.y, wb.z, wb.w};
      float xv[8] = {x0.x, x0.y, x0.z, x0.w, x1.x, x1.y, x1.z, x1.w};
#pragma unroll
      for (int j = 0; j < 8; j++)
#pragma unroll
        for (int p = 0; p < 8; p++) acc[j][p] += xv[p] * wv[j];
    }
    __syncthreads();
#pragma unroll
    for (int j = 0; j < 8; j++) {
      float4 v0, v1;
      float *o0 = &v0.x, *o1 = &v1.x;
#pragma unroll
      for (int p = 0; p < 8; p++) {
        float s = sinf(fqv[j] * acc[j][p] + phv[j]);
        if (p < 4) o0[p] = s; else o1[p - 4] = s;
      }
      int r = 8 * g + j;
      int swz = ((r >> 2) & 7) << 2;
      *((float4 *)&xl[r * 64 + ((8 * h) ^ swz)]) = v0;
      *((float4 *)&xl[r * 64 + ((8 * h + 4) ^ swz)]) = v1;
    }
    __syncthreads();
  }

  // ---- output layer: thread -> (point p = t>>1, channel pair c2 = t&1) ----
  {
    int p = t >> 1, c2 = t & 1;
    const float2 *ow2 = (const float2 *)ow;
    float2 a = ((const float2 *)ob)[c2];
#pragma unroll 4
    for (int k = 0; k < 128; k++) {
      float x = xl[k * 64 + (p ^ (((k >> 2) & 7) << 2))];
      float2 wv = ow2[k * 2 + c2];
      a.x += x * wv.x;
      a.y += x * wv.y;
    }
    if (c2 == 0) {
      a.x = 1.0f / (1.0f + expf(-a.x));
      a.y = 1.0f / (1.0f + expf(-a.y));
    } else {
      a.x = 1.0f / (1.0f + expf(-a.x));
    }
    *((float2 *)&outp[(size_t)(base + p) * 4 + 2 * c2]) = a;
  }
}

// ---------------- coarse weights -> sample_pdf -> fine points ----------------
__global__ __launch_bounds__(256) void k_pdf(const float *zv, const float *coutb,
                                             const float *c2w, float *fz, float *fpts,
                                             unsigned kq0, unsigned kq1, int nrays) {
  int ray = blockIdx.x * 256 + threadIdx.x;
  if (ray >= nrays) return;
  int b = ray / HW, n = ray % HW;
  float z[12];
#pragma unroll
  for (int s = 0; s < 12; s++) z[s] = zv[ray * 12 + s];
  float w[12]; float T = 1.0f;
#pragma unroll
  for (int s = 0; s < 12; s++) {
    float d = (s < 11) ? z[s + 1] - z[s] : 1e10f;
    float sg = coutb[(ray * 12 + s) * 4 + 3];
    float a = 1.0f - expf(-d * fmaxf(sg, 0.0f));
    w[s] = a * T;
    T *= 1.0f - a + 1e-10f;
  }
  float zmid[11];
#pragma unroll
  for (int i = 0; i < 11; i++) zmid[i] = 0.5f * (z[i] + z[i + 1]);
  float pw[10], sum = 0.0f;
#pragma unroll
  for (int i = 0; i < 10; i++) { pw[i] = w[i + 1] + 1e-5f; sum += pw[i]; }
  float cdf[11]; cdf[0] = 0.0f; float cacc = 0.0f;
#pragma unroll
  for (int i = 0; i < 10; i++) { cacc += pw[i] / sum; cdf[i + 1] = cacc; }

  const float *M = c2w + b * 16;
  float m[12];
#pragma unroll
  for (int i = 0; i < 12; i++) m[i] = M[i];
  float dx, dy, dz; pixel_dir(n, dx, dy, dz);
  float tdx = m[0] * dx + m[1] * dy + m[2] * dz;
  float tdy = m[4] * dx + m[5] * dy + m[6] * dz;
  float tdz = m[8] * dx + m[9] * dy + m[10] * dz;
  float ox = m[3], oy = m[7], oz = m[11];

#pragma unroll
  for (int t = 0; t < 12; t++) {
    float u = jax_uniform(kq0, kq1, (unsigned)(ray * 12 + t), (unsigned)(nrays * 12));
    int ind = 0;
#pragma unroll
    for (int i = 0; i < 11; i++) ind += (cdf[i] <= u) ? 1 : 0;  // searchsorted 'right'
    int below = ind - 1; below = below < 0 ? 0 : (below > 10 ? 10 : below);
    int above = ind > 10 ? 10 : ind;
    float cl = 0.f, ch = 0.f, blo = 0.f, bhi = 0.f;
#pragma unroll
    for (int i = 0; i < 11; i++) {
      if (i == below) { cl = cdf[i]; blo = zmid[i]; }
      if (i == above) { ch = cdf[i]; bhi = zmid[i]; }
    }
    float den = ch - cl; if (den < 1e-8f) den = 1.0f;
    float f = blo + (u - cl) / den * (bhi - blo);
    fz[ray * 12 + t] = f;
    fpts[(ray * 12 + t) * 3 + 0] = ox + tdx * f;
    fpts[(ray * 12 + t) * 3 + 1] = oy + tdy * f;
    fpts[(ray * 12 + t) * 3 + 2] = oz + tdz * f;
  }
}

// ---------------- merge (stable sort by z), final integration ----------------
__global__ __launch_bounds__(64) void k_final(const float *zv, const float *fz,
                                              const float *coutb, const float *foutb,
                                              float *outp, int B) {
  __shared__ float L[120 * 64];   // per-thread column: z[24], sig[24], rgb[3][24]
  __shared__ int inv[24 * 64];
  int t = threadIdx.x;
  int ray = blockIdx.x * 64 + t;
  int b = ray / HW, n = ray % HW;
#define SL(e) L[(e) * 64 + t]
  float zr[24];
#pragma unroll
  for (int s = 0; s < 12; s++) {
    float zfv = fz[ray * 12 + s], zcv = zv[ray * 12 + s];
    zr[s] = zfv; zr[12 + s] = zcv;   // concat order: fine first, then coarse
    SL(s) = zfv; SL(12 + s) = zcv;
    SL(24 + s)      = foutb[(ray * 12 + s) * 4 + 3];
    SL(24 + 12 + s) = coutb[(ray * 12 + s) * 4 + 3];
#pragma unroll
    for (int c = 0; c < 3; c++) {
      SL(48 + c * 24 + s)      = foutb[(ray * 12 + s) * 4 + c];
      SL(48 + c * 24 + 12 + s) = coutb[(ray * 12 + s) * 4 + c];
    }
  }
  // stable ranks (ties broken by original index) == JAX stable argsort
#pragma unroll
  for (int i = 0; i < 24; i++) {
    int rank = 0;
#pragma unroll
    for (int j = 0; j < 24; j++)
      rank += (zr[j] < zr[i] || (zr[j] == zr[i] && j < i)) ? 1 : 0;
    inv[rank * 64 + t] = i;
  }
  float Tacc = 1.0f, r0 = 0.f, r1 = 0.f, r2 = 0.f, df = 0.f;
  int icur = inv[0 * 64 + t];
  float zcur = SL(icur);
  for (int r = 0; r < 24; r++) {
    int inext = 0; float znext = 0.f;
    if (r < 23) { inext = inv[(r + 1) * 64 + t]; znext = SL(inext); }
    float d = (r < 23) ? znext - zcur : 1e10f;
    float sg = SL(24 + icur);
    float a = 1.0f - expf(-d * fmaxf(sg, 0.0f));
    float wt = a * Tacc;
    Tacc *= 1.0f - a + 1e-10f;
    r0 += wt * SL(48 + icur);
    r1 += wt * SL(48 + 24 + icur);
    r2 += wt * SL(48 + 48 + icur);
    df += wt * zcur;
    icur = inext; zcur = znext;
  }
#undef SL
  int pi = n >> 6, pj = n & 63;
  float x = -1.0f + (float)pj * (2.0f / 63.0f);
  float y =  1.0f - (float)pi * (2.0f / 63.0f);
  float zc = -1.0f / tanf(0.10471975511965978f);
  float invn = 1.0f / sqrtf(x * x + y * y + zc * zc);
  float mdz = -zc * invn;  // -rays_d.z (positive)
  outp[(b * 3 + 0) * HW + n] = r0 * 2.0f - 1.0f;
  outp[(b * 3 + 1) * HW + n] = r1 * 2.0f - 1.0f;
  outp[(b * 3 + 2) * HW + n] = r2 * 2.0f - 1.0f;
  outp[B * 3 * HW + ray] = df * mdz;
}

extern "C" void kernel_launch(void *const *d_in, const int *in_sizes, int n_in,
                              void *d_out, int out_size, void *d_ws, size_t ws_size,
                              hipStream_t stream) {
  const float *z   = (const float *)d_in[0];
  const float *c2w = (const float *)d_in[1];
  const float *mw0 = (const float *)d_in[2];
  const float *mb0 = (const float *)d_in[3];
  const float *mw1 = (const float *)d_in[4];
  const float *mb1 = (const float *)d_in[5];
  const float *mw2 = (const float *)d_in[6];
  const float *mb2 = (const float *)d_in[7];
  const float *fw  = (const float *)d_in[8];
  const float *fb  = (const float *)d_in[9];
  const float *hw  = (const float *)d_in[10];
  const float *hb  = (const float *)d_in[11];
  const float *ow  = (const float *)d_in[12];
  const float *ob  = (const float *)d_in[13];
  int B = in_sizes[0] / 256;
  int npts = B * PPB;
  int nrays = B * HW;

  float *ws     = (float *)d_ws;
  float *freqs  = ws;
  float *phases = freqs + (size_t)B * 768;
  float *zv     = phases + (size_t)B * 768;
  float *cpts   = zv + npts;
  float *coutb  = cpts + (size_t)npts * 3;
  float *fzv    = coutb + (size_t)npts * 4;
  float *fpts   = fzv + npts;
  float *foutb  = fpts + (size_t)npts * 3;

  // key(42) = [0,42]; split -> k_pert, k_pdf
  unsigned kp0, kp1, kq0, kq1;
#if JAX_PARTITIONABLE
  { unsigned o0, o1;
    tf2x32(0u, 42u, 0u, 0u, o0, o1); kp0 = o0; kp1 = o1;
    tf2x32(0u, 42u, 0u, 1u, o0, o1); kq0 = o0; kq1 = o1; }
#else
  { unsigned a0, a1, c0, c1;
    tf2x32(0u, 42u, 0u, 2u, a0, a1);
    tf2x32(0u, 42u, 1u, 3u, c0, c1);
    kp0 = a0; kp1 = c0; kq0 = a1; kq1 = c1; }
#endif

  k_map<<<B, 256, 0, stream>>>(z, mw0, mb0, mw1, mb1, mw2, mb2, freqs, phases);
  k_rays<<<(npts + 255) / 256, 256, 0, stream>>>(c2w, zv, cpts, kp0, kp1, npts);
  k_siren<<<npts / 64, 128, 0, stream>>>(cpts, freqs, phases, fw, fb, hw, hb, ow, ob, coutb);
  k_pdf<<<(nrays + 255) / 256, 256, 0, stream>>>(zv, coutb, c2w, fzv, fpts, kq0, kq1, nrays);
  k_siren<<<npts / 64, 128, 0, stream>>>(fpts, freqs, phases, fw, fb, hw, hb, ow, ob, foutb);
  k_final<<<nrays / 64, 64, 0, stream>>>(zv, fzv, coutb, foutb, (float *)d_out, B);
}

// Round 6
// 733.192 us; speedup vs baseline: 1.5381x; 1.5381x over previous
//
#include <hip/hip_runtime.h>
#include <hip/hip_bf16.h>

// ---- JAX PRNG variant switches (verified passing in R2) ----
#define JAX_PARTITIONABLE 1
#define PART_MODE 2   // bits = o0 ^ o1

#define HW 4096      // 64*64 pixels
#define NS 12        // num_steps
#define PPB 49152    // HW*NS points per batch element

__host__ __device__ __forceinline__ void tf2x32(unsigned k0, unsigned k1,
                                                unsigned x0, unsigned x1,
                                                unsigned &o0, unsigned &o1) {
  unsigned ks2 = k0 ^ k1 ^ 0x1BD11BDAu;
  unsigned v0 = x0 + k0, v1 = x1 + k1;
#define TFR(r) do { v0 += v1; v1 = (v1 << (r)) | (v1 >> (32 - (r))); v1 ^= v0; } while (0)
  TFR(13); TFR(15); TFR(26); TFR(6);   v0 += k1;  v1 += ks2 + 1u;
  TFR(17); TFR(29); TFR(16); TFR(24);  v0 += ks2; v1 += k0 + 2u;
  TFR(13); TFR(15); TFR(26); TFR(6);   v0 += k0;  v1 += k1 + 3u;
  TFR(17); TFR(29); TFR(16); TFR(24);  v0 += k1;  v1 += ks2 + 4u;
  TFR(13); TFR(15); TFR(26); TFR(6);   v0 += ks2; v1 += k0 + 5u;
#undef TFR
  o0 = v0; o1 = v1;
}

__device__ __forceinline__ float jax_uniform(unsigned k0, unsigned k1,
                                             unsigned idx, unsigned total) {
  unsigned o0, o1, bits;
#if JAX_PARTITIONABLE
  tf2x32(k0, k1, 0u, idx, o0, o1);
#if PART_MODE == 0
  bits = o0;
#elif PART_MODE == 1
  bits = o1;
#else
  bits = o0 ^ o1;
#endif
#else
  unsigned half = total >> 1;
  if (idx < half) { tf2x32(k0, k1, idx, idx + half, o0, o1); bits = o0; }
  else            { tf2x32(k0, k1, idx - half, idx, o0, o1); bits = o1; }
#endif
  return __uint_as_float(0x3f800000u | (bits >> 9)) - 1.0f;
}

__device__ __forceinline__ void pixel_dir(int n, float &dx, float &dy, float &dz) {
  int pi = n >> 6, pj = n & 63;
  float x = -1.0f + (float)pj * (2.0f / 63.0f);
  float y =  1.0f - (float)pi * (2.0f / 63.0f);
  float zc = -1.0f / tanf(0.10471975511965978f);  // deg2rad(12)/2
  float inv = 1.0f / sqrtf(x * x + y * y + zc * zc);
  dx = x * inv; dy = y * inv; dz = zc * inv;
}

// ---------------- mapping network: z(256) -> freqs/phases (768 each) ---------
__global__ __launch_bounds__(256) void k_map(const float *z, const float *w0, const float *b0,
                                             const float *w1, const float *b1,
                                             const float *w2, const float *b2,
                                             float *freqs, float *phases) {
  __shared__ float zl[256], h1[256], h2[256];
  int b = blockIdx.x, t = threadIdx.x;
  zl[t] = z[b * 256 + t];
  __syncthreads();
  float acc = b0[t];
  for (int k = 0; k < 256; k++) acc += zl[k] * w0[k * 256 + t];
  h1[t] = (acc >= 0.0f) ? acc : 0.2f * acc;
  __syncthreads();
  acc = b1[t];
  for (int k = 0; k < 256; k++) acc += h1[k] * w1[k * 256 + t];
  h2[t] = (acc >= 0.0f) ? acc : 0.2f * acc;
  __syncthreads();
  float a6[6];
#pragma unroll
  for (int m = 0; m < 6; m++) a6[m] = b2[t + m * 256];
  for (int k = 0; k < 256; k++) {
    float h = h2[k];
#pragma unroll
    for (int m = 0; m < 6; m++) a6[m] += h * w2[k * 1536 + t + m * 256];
  }
#pragma unroll
  for (int m = 0; m < 6; m++) {
    int o = t + m * 256;
    if (o < 768) freqs[b * 768 + o] = a6[m] * 15.0f + 30.0f;
    else         phases[b * 768 + (o - 768)] = a6[m];
  }
}

// ---------------- coarse rays: perturbed z + transformed points --------------
__global__ __launch_bounds__(256) void k_rays(const float *c2w, float *zv, float *pts,
                                              unsigned kp0, unsigned kp1, int npts) {
  int e = blockIdx.x * 256 + threadIdx.x;
  if (e >= npts) return;
  int b = e / PPB, r = e % PPB, n = r / NS, s = r % NS;
  float dx, dy, dz; pixel_dir(n, dx, dy, dz);
  float delta = (1.12f - 0.88f) / 11.0f;
  float u = jax_uniform(kp0, kp1, (unsigned)e, (unsigned)npts);
  float zval = 0.88f + (float)s * delta + (u - 0.5f) * (float)(0.24 / 11.0);
  zv[e] = zval;
  float px = dx * zval, py = dy * zval, pz = dz * zval;
  const float *M = c2w + b * 16;
  float m[12];
#pragma unroll
  for (int i = 0; i < 12; i++) m[i] = M[i];
  pts[e * 3 + 0] = m[0] * px + m[1] * py + m[2] * pz + m[3];
  pts[e * 3 + 1] = m[4] * px + m[5] * py + m[6] * pz + m[7];
  pts[e * 3 + 2] = m[8] * px + m[9] * py + m[10] * pz + m[11];
}

// ---------------- SIREN forward v4 -------------------------------------------
// Same 8 dims x 8 pts tiling as v3 (0.25 B-LDS/FLOP, VALU-bound design), but:
//  - __launch_bounds__(128, 2): 256-VGPR budget. R4's default heuristic capped
//    at 80 VGPR -> 500+ MB scratch spill traffic (WRITE_SIZE counter). LDS
//    (32KB -> 5 blk/CU = 2.5 waves/SIMD) caps occupancy anyway, so this is free.
//  - no stack arrays in the k-loop: explicit float4-component FMAs (SROA-proof).
//    NB: macro param must NOT be named 'w' (collides with .w member token).
//  - __sinf/__expf (hw v_sin path): ~13% VALU saved, err ~3e-5 << 2.25e-2 thr.
__global__ __launch_bounds__(128, 2) void k_siren(const float *pts, const float *freqs,
                                               const float *phases,
                                               const float *fw, const float *fb,
                                               const float *hw, const float *hb,
                                               const float *ow, const float *ob,
                                               float *outp) {
  __shared__ __align__(16) float xl[128 * 64];
  const int t = threadIdx.x;
  const int g = t & 15;        // dim group: dims 8g..8g+7
  const int h = t >> 4;        // point group: points 8h..8h+7
  const int base = blockIdx.x * 64;
  const int b = base / PPB;

  const float *fqb = freqs + b * 768;
  const float *phb = phases + b * 768;

  // ---- first layer: sin(freq * (pts @ fw + fb) + phase) ----
  {
    float pt[24];
    const float4 *ps = (const float4 *)(pts + (size_t)(base + 8 * h) * 3);
#pragma unroll
    for (int i = 0; i < 6; i++) ((float4 *)pt)[i] = ps[i];
    float fqv[8], phv[8], w0v[8], w1v[8], w2v[8], biv[8];
#pragma unroll
    for (int u = 0; u < 2; u++) {
      ((float4 *)fqv)[u] = ((const float4 *)fqb)[2 * g + u];
      ((float4 *)phv)[u] = ((const float4 *)phb)[2 * g + u];
      ((float4 *)w0v)[u] = ((const float4 *)fw)[2 * g + u];
      ((float4 *)w1v)[u] = ((const float4 *)(fw + 128))[2 * g + u];
      ((float4 *)w2v)[u] = ((const float4 *)(fw + 256))[2 * g + u];
      ((float4 *)biv)[u] = ((const float4 *)fb)[2 * g + u];
    }
#pragma unroll
    for (int j = 0; j < 8; j++) {
      float4 v0, v1;
      v0.x = __sinf(fqv[j] * (pt[0] * w0v[j] + pt[1] * w1v[j] + pt[2] * w2v[j] + biv[j]) + phv[j]);
      v0.y = __sinf(fqv[j] * (pt[3] * w0v[j] + pt[4] * w1v[j] + pt[5] * w2v[j] + biv[j]) + phv[j]);
      v0.z = __sinf(fqv[j] * (pt[6] * w0v[j] + pt[7] * w1v[j] + pt[8] * w2v[j] + biv[j]) + phv[j]);
      v0.w = __sinf(fqv[j] * (pt[9] * w0v[j] + pt[10] * w1v[j] + pt[11] * w2v[j] + biv[j]) + phv[j]);
      v1.x = __sinf(fqv[j] * (pt[12] * w0v[j] + pt[13] * w1v[j] + pt[14] * w2v[j] + biv[j]) + phv[j]);
      v1.y = __sinf(fqv[j] * (pt[15] * w0v[j] + pt[16] * w1v[j] + pt[17] * w2v[j] + biv[j]) + phv[j]);
      v1.z = __sinf(fqv[j] * (pt[18] * w0v[j] + pt[19] * w1v[j] + pt[20] * w2v[j] + biv[j]) + phv[j]);
      v1.w = __sinf(fqv[j] * (pt[21] * w0v[j] + pt[22] * w1v[j] + pt[23] * w2v[j] + biv[j]) + phv[j]);
      int r = 8 * g + j;
      int swz = ((r >> 2) & 7) << 2;
      *((float4 *)&xl[r * 64 + ((8 * h) ^ swz)]) = v0;
      *((float4 *)&xl[r * 64 + ((8 * h + 4) ^ swz)]) = v1;
    }
  }
  __syncthreads();

  // ---- hidden layers ----
#pragma unroll 1
  for (int L = 1; L < 6; L++) {
    float fqv[8], phv[8], biv[8];
#pragma unroll
    for (int u = 0; u < 2; u++) {
      ((float4 *)fqv)[u] = ((const float4 *)(fqb + L * 128))[2 * g + u];
      ((float4 *)phv)[u] = ((const float4 *)(phb + L * 128))[2 * g + u];
      ((float4 *)biv)[u] = ((const float4 *)(hb + (L - 1) * 128))[2 * g + u];
    }
    const float4 *Wl = (const float4 *)(hw + (size_t)(L - 1) * 16384);
    float acc[8][8];
#pragma unroll
    for (int j = 0; j < 8; j++)
#pragma unroll
      for (int p = 0; p < 8; p++) acc[j][p] = biv[j];
#pragma unroll 2
    for (int k = 0; k < 128; k++) {
      float4 wa = Wl[k * 32 + 2 * g];
      float4 wb = Wl[k * 32 + 2 * g + 1];
      int swz = ((k >> 2) & 7) << 2;
      const float4 x0 = *((const float4 *)&xl[k * 64 + ((8 * h) ^ swz)]);
      const float4 x1 = *((const float4 *)&xl[k * 64 + ((8 * h + 4) ^ swz)]);
#define ACCJ(j, WT)                                                           \
      acc[j][0] += x0.x * (WT); acc[j][1] += x0.y * (WT);                     \
      acc[j][2] += x0.z * (WT); acc[j][3] += x0.w * (WT);                     \
      acc[j][4] += x1.x * (WT); acc[j][5] += x1.y * (WT);                     \
      acc[j][6] += x1.z * (WT); acc[j][7] += x1.w * (WT);
      ACCJ(0, wa.x) ACCJ(1, wa.y) ACCJ(2, wa.z) ACCJ(3, wa.w)
      ACCJ(4, wb.x) ACCJ(5, wb.y) ACCJ(6, wb.z) ACCJ(7, wb.w)
#undef ACCJ
    }
    __syncthreads();
#pragma unroll
    for (int j = 0; j < 8; j++) {
      float4 v0, v1;
      v0.x = __sinf(fqv[j] * acc[j][0] + phv[j]);
      v0.y = __sinf(fqv[j] * acc[j][1] + phv[j]);
      v0.z = __sinf(fqv[j] * acc[j][2] + phv[j]);
      v0.w = __sinf(fqv[j] * acc[j][3] + phv[j]);
      v1.x = __sinf(fqv[j] * acc[j][4] + phv[j]);
      v1.y = __sinf(fqv[j] * acc[j][5] + phv[j]);
      v1.z = __sinf(fqv[j] * acc[j][6] + phv[j]);
      v1.w = __sinf(fqv[j] * acc[j][7] + phv[j]);
      int r = 8 * g + j;
      int swz = ((r >> 2) & 7) << 2;
      *((float4 *)&xl[r * 64 + ((8 * h) ^ swz)]) = v0;
      *((float4 *)&xl[r * 64 + ((8 * h + 4) ^ swz)]) = v1;
    }
    __syncthreads();
  }

  // ---- output layer: thread -> (point p = t>>1, channel pair c2 = t&1) ----
  {
    int p = t >> 1, c2 = t & 1;
    const float2 *ow2 = (const float2 *)ow;
    float2 a = ((const float2 *)ob)[c2];
#pragma unroll 4
    for (int k = 0; k < 128; k++) {
      float x = xl[k * 64 + (p ^ (((k >> 2) & 7) << 2))];
      float2 wv = ow2[k * 2 + c2];
      a.x += x * wv.x;
      a.y += x * wv.y;
    }
    if (c2 == 0) {
      a.x = 1.0f / (1.0f + __expf(-a.x));
      a.y = 1.0f / (1.0f + __expf(-a.y));
    } else {
      a.x = 1.0f / (1.0f + __expf(-a.x));
    }
    *((float2 *)&outp[(size_t)(base + p) * 4 + 2 * c2]) = a;
  }
}

// ---------------- coarse weights -> sample_pdf -> fine points ----------------
__global__ __launch_bounds__(256) void k_pdf(const float *zv, const float *coutb,
                                             const float *c2w, float *fz, float *fpts,
                                             unsigned kq0, unsigned kq1, int nrays) {
  int ray = blockIdx.x * 256 + threadIdx.x;
  if (ray >= nrays) return;
  int b = ray / HW, n = ray % HW;
  float z[12];
#pragma unroll
  for (int s = 0; s < 12; s++) z[s] = zv[ray * 12 + s];
  float w[12]; float T = 1.0f;
#pragma unroll
  for (int s = 0; s < 12; s++) {
    float d = (s < 11) ? z[s + 1] - z[s] : 1e10f;
    float sg = coutb[(ray * 12 + s) * 4 + 3];
    float a = 1.0f - expf(-d * fmaxf(sg, 0.0f));
    w[s] = a * T;
    T *= 1.0f - a + 1e-10f;
  }
  float zmid[11];
#pragma unroll
  for (int i = 0; i < 11; i++) zmid[i] = 0.5f * (z[i] + z[i + 1]);
  float pw[10], sum = 0.0f;
#pragma unroll
  for (int i = 0; i < 10; i++) { pw[i] = w[i + 1] + 1e-5f; sum += pw[i]; }
  float cdf[11]; cdf[0] = 0.0f; float cacc = 0.0f;
#pragma unroll
  for (int i = 0; i < 10; i++) { cacc += pw[i] / sum; cdf[i + 1] = cacc; }

  const float *M = c2w + b * 16;
  float m[12];
#pragma unroll
  for (int i = 0; i < 12; i++) m[i] = M[i];
  float dx, dy, dz; pixel_dir(n, dx, dy, dz);
  float tdx = m[0] * dx + m[1] * dy + m[2] * dz;
  float tdy = m[4] * dx + m[5] * dy + m[6] * dz;
  float tdz = m[8] * dx + m[9] * dy + m[10] * dz;
  float ox = m[3], oy = m[7], oz = m[11];

#pragma unroll
  for (int t = 0; t < 12; t++) {
    float u = jax_uniform(kq0, kq1, (unsigned)(ray * 12 + t), (unsigned)(nrays * 12));
    int ind = 0;
#pragma unroll
    for (int i = 0; i < 11; i++) ind += (cdf[i] <= u) ? 1 : 0;  // searchsorted 'right'
    int below = ind - 1; below = below < 0 ? 0 : (below > 10 ? 10 : below);
    int above = ind > 10 ? 10 : ind;
    float cl = 0.f, ch = 0.f, blo = 0.f, bhi = 0.f;
#pragma unroll
    for (int i = 0; i < 11; i++) {
      if (i == below) { cl = cdf[i]; blo = zmid[i]; }
      if (i == above) { ch = cdf[i]; bhi = zmid[i]; }
    }
    float den = ch - cl; if (den < 1e-8f) den = 1.0f;
    float f = blo + (u - cl) / den * (bhi - blo);
    fz[ray * 12 + t] = f;
    fpts[(ray * 12 + t) * 3 + 0] = ox + tdx * f;
    fpts[(ray * 12 + t) * 3 + 1] = oy + tdy * f;
    fpts[(ray * 12 + t) * 3 + 2] = oz + tdz * f;
  }
}

// ---------------- merge (stable sort by z), final integration ----------------
__global__ __launch_bounds__(64) void k_final(const float *zv, const float *fz,
                                              const float *coutb, const float *foutb,
                                              float *outp, int B) {
  __shared__ float L[120 * 64];   // per-thread column: z[24], sig[24], rgb[3][24]
  __shared__ int inv[24 * 64];
  int t = threadIdx.x;
  int ray = blockIdx.x * 64 + t;
  int b = ray / HW, n = ray % HW;
#define SL(e) L[(e) * 64 + t]
  float zr[24];
#pragma unroll
  for (int s = 0; s < 12; s++) {
    float zfv = fz[ray * 12 + s], zcv = zv[ray * 12 + s];
    zr[s] = zfv; zr[12 + s] = zcv;   // concat order: fine first, then coarse
    SL(s) = zfv; SL(12 + s) = zcv;
    SL(24 + s)      = foutb[(ray * 12 + s) * 4 + 3];
    SL(24 + 12 + s) = coutb[(ray * 12 + s) * 4 + 3];
#pragma unroll
    for (int c = 0; c < 3; c++) {
      SL(48 + c * 24 + s)      = foutb[(ray * 12 + s) * 4 + c];
      SL(48 + c * 24 + 12 + s) = coutb[(ray * 12 + s) * 4 + c];
    }
  }
  // stable ranks (ties broken by original index) == JAX stable argsort
#pragma unroll
  for (int i = 0; i < 24; i++) {
    int rank = 0;
#pragma unroll
    for (int j = 0; j < 24; j++)
      rank += (zr[j] < zr[i] || (zr[j] == zr[i] && j < i)) ? 1 : 0;
    inv[rank * 64 + t] = i;
  }
  float Tacc = 1.0f, r0 = 0.f, r1 = 0.f, r2 = 0.f, df = 0.f;
  int icur = inv[0 * 64 + t];
  float zcur = SL(icur);
  for (int r = 0; r < 24; r++) {
    int inext = 0; float znext = 0.f;
    if (r < 23) { inext = inv[(r + 1) * 64 + t]; znext = SL(inext); }
    float d = (r < 23) ? znext - zcur : 1e10f;
    float sg = SL(24 + icur);
    float a = 1.0f - expf(-d * fmaxf(sg, 0.0f));
    float wt = a * Tacc;
    Tacc *= 1.0f - a + 1e-10f;
    r0 += wt * SL(48 + icur);
    r1 += wt * SL(48 + 24 + icur);
    r2 += wt * SL(48 + 48 + icur);
    df += wt * zcur;
    icur = inext; zcur = znext;
  }
#undef SL
  int pi = n >> 6, pj = n & 63;
  float x = -1.0f + (float)pj * (2.0f / 63.0f);
  float y =  1.0f - (float)pi * (2.0f / 63.0f);
  float zc = -1.0f / tanf(0.10471975511965978f);
  float invn = 1.0f / sqrtf(x * x + y * y + zc * zc);
  float mdz = -zc * invn;  // -rays_d.z (positive)
  outp[(b * 3 + 0) * HW + n] = r0 * 2.0f - 1.0f;
  outp[(b * 3 + 1) * HW + n] = r1 * 2.0f - 1.0f;
  outp[(b * 3 + 2) * HW + n] = r2 * 2.0f - 1.0f;
  outp[B * 3 * HW + ray] = df * mdz;
}

extern "C" void kernel_launch(void *const *d_in, const int *in_sizes, int n_in,
                              void *d_out, int out_size, void *d_ws, size_t ws_size,
                              hipStream_t stream) {
  const float *z   = (const float *)d_in[0];
  const float *c2w = (const float *)d_in[1];
  const float *mw0 = (const float *)d_in[2];
  const float *mb0 = (const float *)d_in[3];
  const float *mw1 = (const float *)d_in[4];
  const float *mb1 = (const float *)d_in[5];
  const float *mw2 = (const float *)d_in[6];
  const float *mb2 = (const float *)d_in[7];
  const float *fw  = (const float *)d_in[8];
  const float *fb  = (const float *)d_in[9];
  const float *hw  = (const float *)d_in[10];
  const float *hb  = (const float *)d_in[11];
  const float *ow  = (const float *)d_in[12];
  const float *ob  = (const float *)d_in[13];
  int B = in_sizes[0] / 256;
  int npts = B * PPB;
  int nrays = B * HW;

  float *ws     = (float *)d_ws;
  float *freqs  = ws;
  float *phases = freqs + (size_t)B * 768;
  float *zv     = phases + (size_t)B * 768;
  float *cpts   = zv + npts;
  float *coutb  = cpts + (size_t)npts * 3;
  float *fzv    = coutb + (size_t)npts * 4;
  float *fpts   = fzv + npts;
  float *foutb  = fpts + (size_t)npts * 3;

  // key(42) = [0,42]; split -> k_pert, k_pdf
  unsigned kp0, kp1, kq0, kq1;
#if JAX_PARTITIONABLE
  { unsigned o0, o1;
    tf2x32(0u, 42u, 0u, 0u, o0, o1); kp0 = o0; kp1 = o1;
    tf2x32(0u, 42u, 0u, 1u, o0, o1); kq0 = o0; kq1 = o1; }
#else
  { unsigned a0, a1, c0, c1;
    tf2x32(0u, 42u, 0u, 2u, a0, a1);
    tf2x32(0u, 42u, 1u, 3u, c0, c1);
    kp0 = a0; kp1 = c0; kq0 = a1; kq1 = c1; }
#endif

  k_map<<<B, 256, 0, stream>>>(z, mw0, mb0, mw1, mb1, mw2, mb2, freqs, phases);
  k_rays<<<(npts + 255) / 256, 256, 0, stream>>>(c2w, zv, cpts, kp0, kp1, npts);
  k_siren<<<npts / 64, 128, 0, stream>>>(cpts, freqs, phases, fw, fb, hw, hb, ow, ob, coutb);
  k_pdf<<<(nrays + 255) / 256, 256, 0, stream>>>(zv, coutb, c2w, fzv, fpts, kq0, kq1, nrays);
  k_siren<<<npts / 64, 128, 0, stream>>>(fpts, freqs, phases, fw, fb, hw, hb, ow, ob, foutb);
  k_final<<<nrays / 64, 64, 0, stream>>>(zv, fzv, coutb, foutb, (float *)d_out, B);
}

// Round 7
// 711.102 us; speedup vs baseline: 1.5859x; 1.0311x over previous
//
#include <hip/hip_runtime.h>
#include <hip/hip_bf16.h>

// ---- JAX PRNG variant switches (verified passing in R2) ----
#define JAX_PARTITIONABLE 1
#define PART_MODE 2   // bits = o0 ^ o1

#define HW 4096      // 64*64 pixels
#define NS 12        // num_steps
#define PPB 49152    // HW*NS points per batch element

__host__ __device__ __forceinline__ void tf2x32(unsigned k0, unsigned k1,
                                                unsigned x0, unsigned x1,
                                                unsigned &o0, unsigned &o1) {
  unsigned ks2 = k0 ^ k1 ^ 0x1BD11BDAu;
  unsigned v0 = x0 + k0, v1 = x1 + k1;
#define TFR(r) do { v0 += v1; v1 = (v1 << (r)) | (v1 >> (32 - (r))); v1 ^= v0; } while (0)
  TFR(13); TFR(15); TFR(26); TFR(6);   v0 += k1;  v1 += ks2 + 1u;
  TFR(17); TFR(29); TFR(16); TFR(24);  v0 += ks2; v1 += k0 + 2u;
  TFR(13); TFR(15); TFR(26); TFR(6);   v0 += k0;  v1 += k1 + 3u;
  TFR(17); TFR(29); TFR(16); TFR(24);  v0 += k1;  v1 += ks2 + 4u;
  TFR(13); TFR(15); TFR(26); TFR(6);   v0 += ks2; v1 += k0 + 5u;
#undef TFR
  o0 = v0; o1 = v1;
}

__device__ __forceinline__ float jax_uniform(unsigned k0, unsigned k1,
                                             unsigned idx, unsigned total) {
  unsigned o0, o1, bits;
#if JAX_PARTITIONABLE
  tf2x32(k0, k1, 0u, idx, o0, o1);
#if PART_MODE == 0
  bits = o0;
#elif PART_MODE == 1
  bits = o1;
#else
  bits = o0 ^ o1;
#endif
#else
  unsigned half = total >> 1;
  if (idx < half) { tf2x32(k0, k1, idx, idx + half, o0, o1); bits = o0; }
  else            { tf2x32(k0, k1, idx - half, idx, o0, o1); bits = o1; }
#endif
  return __uint_as_float(0x3f800000u | (bits >> 9)) - 1.0f;
}

__device__ __forceinline__ void pixel_dir(int n, float &dx, float &dy, float &dz) {
  int pi = n >> 6, pj = n & 63;
  float x = -1.0f + (float)pj * (2.0f / 63.0f);
  float y =  1.0f - (float)pi * (2.0f / 63.0f);
  float zc = -1.0f / tanf(0.10471975511965978f);  // deg2rad(12)/2
  float inv = 1.0f / sqrtf(x * x + y * y + zc * zc);
  dx = x * inv; dy = y * inv; dz = zc * inv;
}

// ---------------- mapping network: z(256) -> freqs/phases (768 each) ---------
__global__ __launch_bounds__(256) void k_map(const float *z, const float *w0, const float *b0,
                                             const float *w1, const float *b1,
                                             const float *w2, const float *b2,
                                             float *freqs, float *phases) {
  __shared__ float zl[256], h1[256], h2[256];
  int b = blockIdx.x, t = threadIdx.x;
  zl[t] = z[b * 256 + t];
  __syncthreads();
  float acc = b0[t];
  for (int k = 0; k < 256; k++) acc += zl[k] * w0[k * 256 + t];
  h1[t] = (acc >= 0.0f) ? acc : 0.2f * acc;
  __syncthreads();
  acc = b1[t];
  for (int k = 0; k < 256; k++) acc += h1[k] * w1[k * 256 + t];
  h2[t] = (acc >= 0.0f) ? acc : 0.2f * acc;
  __syncthreads();
  float a6[6];
#pragma unroll
  for (int m = 0; m < 6; m++) a6[m] = b2[t + m * 256];
  for (int k = 0; k < 256; k++) {
    float h = h2[k];
#pragma unroll
    for (int m = 0; m < 6; m++) a6[m] += h * w2[k * 1536 + t + m * 256];
  }
#pragma unroll
  for (int m = 0; m < 6; m++) {
    int o = t + m * 256;
    if (o < 768) freqs[b * 768 + o] = a6[m] * 15.0f + 30.0f;
    else         phases[b * 768 + (o - 768)] = a6[m];
  }
}

// ---------------- coarse rays: perturbed z + transformed points --------------
__global__ __launch_bounds__(256) void k_rays(const float *c2w, float *zv, float *pts,
                                              unsigned kp0, unsigned kp1, int npts) {
  int e = blockIdx.x * 256 + threadIdx.x;
  if (e >= npts) return;
  int b = e / PPB, r = e % PPB, n = r / NS, s = r % NS;
  float dx, dy, dz; pixel_dir(n, dx, dy, dz);
  float delta = (1.12f - 0.88f) / 11.0f;
  float u = jax_uniform(kp0, kp1, (unsigned)e, (unsigned)npts);
  float zval = 0.88f + (float)s * delta + (u - 0.5f) * (float)(0.24 / 11.0);
  zv[e] = zval;
  float px = dx * zval, py = dy * zval, pz = dz * zval;
  const float *M = c2w + b * 16;
  float m[12];
#pragma unroll
  for (int i = 0; i < 12; i++) m[i] = M[i];
  pts[e * 3 + 0] = m[0] * px + m[1] * py + m[2] * pz + m[3];
  pts[e * 3 + 1] = m[4] * px + m[5] * py + m[6] * pz + m[7];
  pts[e * 3 + 2] = m[8] * px + m[9] * py + m[10] * pz + m[11];
}

// ---------------- SIREN forward v5 -------------------------------------------
// 8 dims x 8 pts per thread (0.25 B-LDS/FLOP), spill-free at launch_bounds(128,2).
// R6 showed 2.8x over issue floor: unpipelined k-loop (load->wait->fma ~410cyc/k)
// at ~1.2 waves/SIMD. v5: manual dist-2 software pipeline (loads for k,k+1 issued
// before FMAs of k-2,k-1; ~290cyc in flight covers LDS ~120 + L2 ~250) and
// revolutions-domain v_sin (pre-scaled freq/phase by 1/2pi, kills per-sin mul).
#define INV2PI 0.15915494309189535f

__global__ __launch_bounds__(128, 2) void k_siren(const float *pts, const float *freqs,
                                               const float *phases,
                                               const float *fw, const float *fb,
                                               const float *hw, const float *hb,
                                               const float *ow, const float *ob,
                                               float *outp) {
  __shared__ __align__(16) float xl[128 * 64];
  const int t = threadIdx.x;
  const int g = t & 15;        // dim group: dims 8g..8g+7
  const int h = t >> 4;        // point group: points 8h..8h+7
  const int base = blockIdx.x * 64;
  const int b = base / PPB;

  const float *fqb = freqs + b * 768;
  const float *phb = phases + b * 768;

  // ---- first layer: sin(freq * (pts @ fw + fb) + phase) ----
  {
    float pt[24];
    const float4 *ps = (const float4 *)(pts + (size_t)(base + 8 * h) * 3);
#pragma unroll
    for (int i = 0; i < 6; i++) ((float4 *)pt)[i] = ps[i];
    float fqv[8], phv[8], w0v[8], w1v[8], w2v[8], biv[8];
#pragma unroll
    for (int u = 0; u < 2; u++) {
      ((float4 *)fqv)[u] = ((const float4 *)fqb)[2 * g + u];
      ((float4 *)phv)[u] = ((const float4 *)phb)[2 * g + u];
      ((float4 *)w0v)[u] = ((const float4 *)fw)[2 * g + u];
      ((float4 *)w1v)[u] = ((const float4 *)(fw + 128))[2 * g + u];
      ((float4 *)w2v)[u] = ((const float4 *)(fw + 256))[2 * g + u];
      ((float4 *)biv)[u] = ((const float4 *)fb)[2 * g + u];
    }
#pragma unroll
    for (int j = 0; j < 8; j++) {
      float fr = fqv[j] * INV2PI, pr = phv[j] * INV2PI;
      float4 v0, v1;
      v0.x = __builtin_amdgcn_sinf(fr * (pt[0] * w0v[j] + pt[1] * w1v[j] + pt[2] * w2v[j] + biv[j]) + pr);
      v0.y = __builtin_amdgcn_sinf(fr * (pt[3] * w0v[j] + pt[4] * w1v[j] + pt[5] * w2v[j] + biv[j]) + pr);
      v0.z = __builtin_amdgcn_sinf(fr * (pt[6] * w0v[j] + pt[7] * w1v[j] + pt[8] * w2v[j] + biv[j]) + pr);
      v0.w = __builtin_amdgcn_sinf(fr * (pt[9] * w0v[j] + pt[10] * w1v[j] + pt[11] * w2v[j] + biv[j]) + pr);
      v1.x = __builtin_amdgcn_sinf(fr * (pt[12] * w0v[j] + pt[13] * w1v[j] + pt[14] * w2v[j] + biv[j]) + pr);
      v1.y = __builtin_amdgcn_sinf(fr * (pt[15] * w0v[j] + pt[16] * w1v[j] + pt[17] * w2v[j] + biv[j]) + pr);
      v1.z = __builtin_amdgcn_sinf(fr * (pt[18] * w0v[j] + pt[19] * w1v[j] + pt[20] * w2v[j] + biv[j]) + pr);
      v1.w = __builtin_amdgcn_sinf(fr * (pt[21] * w0v[j] + pt[22] * w1v[j] + pt[23] * w2v[j] + biv[j]) + pr);
      int r = 8 * g + j;
      int swz = ((r >> 2) & 7) << 2;
      *((float4 *)&xl[r * 64 + ((8 * h) ^ swz)]) = v0;
      *((float4 *)&xl[r * 64 + ((8 * h + 4) ^ swz)]) = v1;
    }
  }
  __syncthreads();

  // ---- hidden layers: dist-2 software-pipelined k-loop ----
#define WA(k) (Wl[(k) * 32 + 2 * g])
#define WB(k) (Wl[(k) * 32 + 2 * g + 1])
#define XLO(k) (*(const float4 *)&xl[(k) * 64 + ((8 * h) ^ ((((k) >> 2) & 7) << 2))])
#define XHI(k) (*(const float4 *)&xl[(k) * 64 + ((8 * h + 4) ^ ((((k) >> 2) & 7) << 2))])
#define ACCJ(j, WT, X0V, X1V)                                                 \
      acc[j][0] += (X0V).x * (WT); acc[j][1] += (X0V).y * (WT);               \
      acc[j][2] += (X0V).z * (WT); acc[j][3] += (X0V).w * (WT);               \
      acc[j][4] += (X1V).x * (WT); acc[j][5] += (X1V).y * (WT);               \
      acc[j][6] += (X1V).z * (WT); acc[j][7] += (X1V).w * (WT);
#define FMAS(WAV, WBV, X0V, X1V)                                              \
      do {                                                                    \
        ACCJ(0, (WAV).x, X0V, X1V) ACCJ(1, (WAV).y, X0V, X1V)                 \
        ACCJ(2, (WAV).z, X0V, X1V) ACCJ(3, (WAV).w, X0V, X1V)                 \
        ACCJ(4, (WBV).x, X0V, X1V) ACCJ(5, (WBV).y, X0V, X1V)                 \
        ACCJ(6, (WBV).z, X0V, X1V) ACCJ(7, (WBV).w, X0V, X1V)                 \
      } while (0)

#pragma unroll 1
  for (int L = 1; L < 6; L++) {
    float fqv[8], phv[8], biv[8];
#pragma unroll
    for (int u = 0; u < 2; u++) {
      ((float4 *)fqv)[u] = ((const float4 *)(fqb + L * 128))[2 * g + u];
      ((float4 *)phv)[u] = ((const float4 *)(phb + L * 128))[2 * g + u];
      ((float4 *)biv)[u] = ((const float4 *)(hb + (L - 1) * 128))[2 * g + u];
    }
    const float4 *Wl = (const float4 *)(hw + (size_t)(L - 1) * 16384);
    float acc[8][8];
#pragma unroll
    for (int j = 0; j < 8; j++)
#pragma unroll
      for (int p = 0; p < 8; p++) acc[j][p] = biv[j];

    float4 wa0 = WA(0), wb0 = WB(0), x00 = XLO(0), x10 = XHI(0);
    float4 wa1 = WA(1), wb1 = WB(1), x01 = XLO(1), x11 = XHI(1);
#pragma unroll 1
    for (int k = 2; k < 128; k += 2) {
      float4 nwa0 = WA(k), nwb0 = WB(k), nx00 = XLO(k), nx10 = XHI(k);
      float4 nwa1 = WA(k + 1), nwb1 = WB(k + 1), nx01 = XLO(k + 1), nx11 = XHI(k + 1);
      FMAS(wa0, wb0, x00, x10);
      FMAS(wa1, wb1, x01, x11);
      wa0 = nwa0; wb0 = nwb0; x00 = nx00; x10 = nx10;
      wa1 = nwa1; wb1 = nwb1; x01 = nx01; x11 = nx11;
    }
    FMAS(wa0, wb0, x00, x10);
    FMAS(wa1, wb1, x01, x11);

    __syncthreads();
#pragma unroll
    for (int j = 0; j < 8; j++) {
      float fr = fqv[j] * INV2PI, pr = phv[j] * INV2PI;
      float4 v0, v1;
      v0.x = __builtin_amdgcn_sinf(fr * acc[j][0] + pr);
      v0.y = __builtin_amdgcn_sinf(fr * acc[j][1] + pr);
      v0.z = __builtin_amdgcn_sinf(fr * acc[j][2] + pr);
      v0.w = __builtin_amdgcn_sinf(fr * acc[j][3] + pr);
      v1.x = __builtin_amdgcn_sinf(fr * acc[j][4] + pr);
      v1.y = __builtin_amdgcn_sinf(fr * acc[j][5] + pr);
      v1.z = __builtin_amdgcn_sinf(fr * acc[j][6] + pr);
      v1.w = __builtin_amdgcn_sinf(fr * acc[j][7] + pr);
      int r = 8 * g + j;
      int swz = ((r >> 2) & 7) << 2;
      *((float4 *)&xl[r * 64 + ((8 * h) ^ swz)]) = v0;
      *((float4 *)&xl[r * 64 + ((8 * h + 4) ^ swz)]) = v1;
    }
    __syncthreads();
  }
#undef FMAS
#undef ACCJ
#undef WA
#undef WB
#undef XLO
#undef XHI

  // ---- output layer: thread -> (point p = t>>1, channel pair c2 = t&1) ----
  {
    int p = t >> 1, c2 = t & 1;
    const float2 *ow2 = (const float2 *)ow;
    float2 a = ((const float2 *)ob)[c2];
#pragma unroll 4
    for (int k = 0; k < 128; k++) {
      float x = xl[k * 64 + (p ^ (((k >> 2) & 7) << 2))];
      float2 wv = ow2[k * 2 + c2];
      a.x += x * wv.x;
      a.y += x * wv.y;
    }
    if (c2 == 0) {
      a.x = 1.0f / (1.0f + __expf(-a.x));
      a.y = 1.0f / (1.0f + __expf(-a.y));
    } else {
      a.x = 1.0f / (1.0f + __expf(-a.x));
    }
    *((float2 *)&outp[(size_t)(base + p) * 4 + 2 * c2]) = a;
  }
}

// ---------------- coarse weights -> sample_pdf -> fine points ----------------
__global__ __launch_bounds__(256) void k_pdf(const float *zv, const float *coutb,
                                             const float *c2w, float *fz, float *fpts,
                                             unsigned kq0, unsigned kq1, int nrays) {
  int ray = blockIdx.x * 256 + threadIdx.x;
  if (ray >= nrays) return;
  int b = ray / HW, n = ray % HW;
  float z[12];
#pragma unroll
  for (int s = 0; s < 12; s++) z[s] = zv[ray * 12 + s];
  float w[12]; float T = 1.0f;
#pragma unroll
  for (int s = 0; s < 12; s++) {
    float d = (s < 11) ? z[s + 1] - z[s] : 1e10f;
    float sg = coutb[(ray * 12 + s) * 4 + 3];
    float a = 1.0f - expf(-d * fmaxf(sg, 0.0f));
    w[s] = a * T;
    T *= 1.0f - a + 1e-10f;
  }
  float zmid[11];
#pragma unroll
  for (int i = 0; i < 11; i++) zmid[i] = 0.5f * (z[i] + z[i + 1]);
  float pw[10], sum = 0.0f;
#pragma unroll
  for (int i = 0; i < 10; i++) { pw[i] = w[i + 1] + 1e-5f; sum += pw[i]; }
  float cdf[11]; cdf[0] = 0.0f; float cacc = 0.0f;
#pragma unroll
  for (int i = 0; i < 10; i++) { cacc += pw[i] / sum; cdf[i + 1] = cacc; }

  const float *M = c2w + b * 16;
  float m[12];
#pragma unroll
  for (int i = 0; i < 12; i++) m[i] = M[i];
  float dx, dy, dz; pixel_dir(n, dx, dy, dz);
  float tdx = m[0] * dx + m[1] * dy + m[2] * dz;
  float tdy = m[4] * dx + m[5] * dy + m[6] * dz;
  float tdz = m[8] * dx + m[9] * dy + m[10] * dz;
  float ox = m[3], oy = m[7], oz = m[11];

#pragma unroll
  for (int t = 0; t < 12; t++) {
    float u = jax_uniform(kq0, kq1, (unsigned)(ray * 12 + t), (unsigned)(nrays * 12));
    int ind = 0;
#pragma unroll
    for (int i = 0; i < 11; i++) ind += (cdf[i] <= u) ? 1 : 0;  // searchsorted 'right'
    int below = ind - 1; below = below < 0 ? 0 : (below > 10 ? 10 : below);
    int above = ind > 10 ? 10 : ind;
    float cl = 0.f, ch = 0.f, blo = 0.f, bhi = 0.f;
#pragma unroll
    for (int i = 0; i < 11; i++) {
      if (i == below) { cl = cdf[i]; blo = zmid[i]; }
      if (i == above) { ch = cdf[i]; bhi = zmid[i]; }
    }
    float den = ch - cl; if (den < 1e-8f) den = 1.0f;
    float f = blo + (u - cl) / den * (bhi - blo);
    fz[ray * 12 + t] = f;
    fpts[(ray * 12 + t) * 3 + 0] = ox + tdx * f;
    fpts[(ray * 12 + t) * 3 + 1] = oy + tdy * f;
    fpts[(ray * 12 + t) * 3 + 2] = oz + tdz * f;
  }
}

// ---------------- merge (stable sort by z), final integration ----------------
__global__ __launch_bounds__(64) void k_final(const float *zv, const float *fz,
                                              const float *coutb, const float *foutb,
                                              float *outp, int B) {
  __shared__ float L[120 * 64];   // per-thread column: z[24], sig[24], rgb[3][24]
  __shared__ int inv[24 * 64];
  int t = threadIdx.x;
  int ray = blockIdx.x * 64 + t;
  int b = ray / HW, n = ray % HW;
#define SL(e) L[(e) * 64 + t]
  float zr[24];
#pragma unroll
  for (int s = 0; s < 12; s++) {
    float zfv = fz[ray * 12 + s], zcv = zv[ray * 12 + s];
    zr[s] = zfv; zr[12 + s] = zcv;   // concat order: fine first, then coarse
    SL(s) = zfv; SL(12 + s) = zcv;
    SL(24 + s)      = foutb[(ray * 12 + s) * 4 + 3];
    SL(24 + 12 + s) = coutb[(ray * 12 + s) * 4 + 3];
#pragma unroll
    for (int c = 0; c < 3; c++) {
      SL(48 + c * 24 + s)      = foutb[(ray * 12 + s) * 4 + c];
      SL(48 + c * 24 + 12 + s) = coutb[(ray * 12 + s) * 4 + c];
    }
  }
  // stable ranks (ties broken by original index) == JAX stable argsort
#pragma unroll
  for (int i = 0; i < 24; i++) {
    int rank = 0;
#pragma unroll
    for (int j = 0; j < 24; j++)
      rank += (zr[j] < zr[i] || (zr[j] == zr[i] && j < i)) ? 1 : 0;
    inv[rank * 64 + t] = i;
  }
  float Tacc = 1.0f, r0 = 0.f, r1 = 0.f, r2 = 0.f, df = 0.f;
  int icur = inv[0 * 64 + t];
  float zcur = SL(icur);
  for (int r = 0; r < 24; r++) {
    int inext = 0; float znext = 0.f;
    if (r < 23) { inext = inv[(r + 1) * 64 + t]; znext = SL(inext); }
    float d = (r < 23) ? znext - zcur : 1e10f;
    float sg = SL(24 + icur);
    float a = 1.0f - expf(-d * fmaxf(sg, 0.0f));
    float wt = a * Tacc;
    Tacc *= 1.0f - a + 1e-10f;
    r0 += wt * SL(48 + icur);
    r1 += wt * SL(48 + 24 + icur);
    r2 += wt * SL(48 + 48 + icur);
    df += wt * zcur;
    icur = inext; zcur = znext;
  }
#undef SL
  int pi = n >> 6, pj = n & 63;
  float x = -1.0f + (float)pj * (2.0f / 63.0f);
  float y =  1.0f - (float)pi * (2.0f / 63.0f);
  float zc = -1.0f / tanf(0.10471975511965978f);
  float invn = 1.0f / sqrtf(x * x + y * y + zc * zc);
  float mdz = -zc * invn;  // -rays_d.z (positive)
  outp[(b * 3 + 0) * HW + n] = r0 * 2.0f - 1.0f;
  outp[(b * 3 + 1) * HW + n] = r1 * 2.0f - 1.0f;
  outp[(b * 3 + 2) * HW + n] = r2 * 2.0f - 1.0f;
  outp[B * 3 * HW + ray] = df * mdz;
}

extern "C" void kernel_launch(void *const *d_in, const int *in_sizes, int n_in,
                              void *d_out, int out_size, void *d_ws, size_t ws_size,
                              hipStream_t stream) {
  const float *z   = (const float *)d_in[0];
  const float *c2w = (const float *)d_in[1];
  const float *mw0 = (const float *)d_in[2];
  const float *mb0 = (const float *)d_in[3];
  const float *mw1 = (const float *)d_in[4];
  const float *mb1 = (const float *)d_in[5];
  const float *mw2 = (const float *)d_in[6];
  const float *mb2 = (const float *)d_in[7];
  const float *fw  = (const float *)d_in[8];
  const float *fb  = (const float *)d_in[9];
  const float *hw  = (const float *)d_in[10];
  const float *hb  = (const float *)d_in[11];
  const float *ow  = (const float *)d_in[12];
  const float *ob  = (const float *)d_in[13];
  int B = in_sizes[0] / 256;
  int npts = B * PPB;
  int nrays = B * HW;

  float *ws     = (float *)d_ws;
  float *freqs  = ws;
  float *phases = freqs + (size_t)B * 768;
  float *zv     = phases + (size_t)B * 768;
  float *cpts   = zv + npts;
  float *coutb  = cpts + (size_t)npts * 3;
  float *fzv    = coutb + (size_t)npts * 4;
  float *fpts   = fzv + npts;
  float *foutb  = fpts + (size_t)npts * 3;

  // key(42) = [0,42]; split -> k_pert, k_pdf
  unsigned kp0, kp1, kq0, kq1;
#if JAX_PARTITIONABLE
  { unsigned o0, o1;
    tf2x32(0u, 42u, 0u, 0u, o0, o1); kp0 = o0; kp1 = o1;
    tf2x32(0u, 42u, 0u, 1u, o0, o1); kq0 = o0; kq1 = o1; }
#else
  { unsigned a0, a1, c0, c1;
    tf2x32(0u, 42u, 0u, 2u, a0, a1);
    tf2x32(0u, 42u, 1u, 3u, c0, c1);
    kp0 = a0; kp1 = c0; kq0 = a1; kq1 = c1; }
#endif

  k_map<<<B, 256, 0, stream>>>(z, mw0, mb0, mw1, mb1, mw2, mb2, freqs, phases);
  k_rays<<<(npts + 255) / 256, 256, 0, stream>>>(c2w, zv, cpts, kp0, kp1, npts);
  k_siren<<<npts / 64, 128, 0, stream>>>(cpts, freqs, phases, fw, fb, hw, hb, ow, ob, coutb);
  k_pdf<<<(nrays + 255) / 256, 256, 0, stream>>>(zv, coutb, c2w, fzv, fpts, kq0, kq1, nrays);
  k_siren<<<npts / 64, 128, 0, stream>>>(fpts, freqs, phases, fw, fb, hw, hb, ow, ob, foutb);
  k_final<<<nrays / 64, 64, 0, stream>>>(zv, fzv, coutb, foutb, (float *)d_out, B);
}

// Round 8
// 654.328 us; speedup vs baseline: 1.7235x; 1.0868x over previous
//
#include <hip/hip_runtime.h>
#include <hip/hip_bf16.h>

// ---- JAX PRNG variant switches (verified passing in R2) ----
#define JAX_PARTITIONABLE 1
#define PART_MODE 2   // bits = o0 ^ o1

#define HW 4096      // 64*64 pixels
#define NS 12        // num_steps
#define PPB 49152    // HW*NS points per batch element

__host__ __device__ __forceinline__ void tf2x32(unsigned k0, unsigned k1,
                                                unsigned x0, unsigned x1,
                                                unsigned &o0, unsigned &o1) {
  unsigned ks2 = k0 ^ k1 ^ 0x1BD11BDAu;
  unsigned v0 = x0 + k0, v1 = x1 + k1;
#define TFR(r) do { v0 += v1; v1 = (v1 << (r)) | (v1 >> (32 - (r))); v1 ^= v0; } while (0)
  TFR(13); TFR(15); TFR(26); TFR(6);   v0 += k1;  v1 += ks2 + 1u;
  TFR(17); TFR(29); TFR(16); TFR(24);  v0 += ks2; v1 += k0 + 2u;
  TFR(13); TFR(15); TFR(26); TFR(6);   v0 += k0;  v1 += k1 + 3u;
  TFR(17); TFR(29); TFR(16); TFR(24);  v0 += k1;  v1 += ks2 + 4u;
  TFR(13); TFR(15); TFR(26); TFR(6);   v0 += ks2; v1 += k0 + 5u;
#undef TFR
  o0 = v0; o1 = v1;
}

__device__ __forceinline__ float jax_uniform(unsigned k0, unsigned k1,
                                             unsigned idx, unsigned total) {
  unsigned o0, o1, bits;
#if JAX_PARTITIONABLE
  tf2x32(k0, k1, 0u, idx, o0, o1);
#if PART_MODE == 0
  bits = o0;
#elif PART_MODE == 1
  bits = o1;
#else
  bits = o0 ^ o1;
#endif
#else
  unsigned half = total >> 1;
  if (idx < half) { tf2x32(k0, k1, idx, idx + half, o0, o1); bits = o0; }
  else            { tf2x32(k0, k1, idx - half, idx, o0, o1); bits = o1; }
#endif
  return __uint_as_float(0x3f800000u | (bits >> 9)) - 1.0f;
}

__device__ __forceinline__ void pixel_dir(int n, float &dx, float &dy, float &dz) {
  int pi = n >> 6, pj = n & 63;
  float x = -1.0f + (float)pj * (2.0f / 63.0f);
  float y =  1.0f - (float)pi * (2.0f / 63.0f);
  float zc = -1.0f / tanf(0.10471975511965978f);  // deg2rad(12)/2
  float inv = 1.0f / sqrtf(x * x + y * y + zc * zc);
  dx = x * inv; dy = y * inv; dz = zc * inv;
}

// ---------------- mapping network: z(256) -> freqs/phases (768 each) ---------
__global__ __launch_bounds__(256) void k_map(const float *z, const float *w0, const float *b0,
                                             const float *w1, const float *b1,
                                             const float *w2, const float *b2,
                                             float *freqs, float *phases) {
  __shared__ float zl[256], h1[256], h2[256];
  int b = blockIdx.x, t = threadIdx.x;
  zl[t] = z[b * 256 + t];
  __syncthreads();
  float acc = b0[t];
  for (int k = 0; k < 256; k++) acc += zl[k] * w0[k * 256 + t];
  h1[t] = (acc >= 0.0f) ? acc : 0.2f * acc;
  __syncthreads();
  acc = b1[t];
  for (int k = 0; k < 256; k++) acc += h1[k] * w1[k * 256 + t];
  h2[t] = (acc >= 0.0f) ? acc : 0.2f * acc;
  __syncthreads();
  float a6[6];
#pragma unroll
  for (int m = 0; m < 6; m++) a6[m] = b2[t + m * 256];
  for (int k = 0; k < 256; k++) {
    float h = h2[k];
#pragma unroll
    for (int m = 0; m < 6; m++) a6[m] += h * w2[k * 1536 + t + m * 256];
  }
#pragma unroll
  for (int m = 0; m < 6; m++) {
    int o = t + m * 256;
    if (o < 768) freqs[b * 768 + o] = a6[m] * 15.0f + 30.0f;
    else         phases[b * 768 + (o - 768)] = a6[m];
  }
}

// ---------------- coarse rays: perturbed z + transformed points --------------
__global__ __launch_bounds__(256) void k_rays(const float *c2w, float *zv, float *pts,
                                              unsigned kp0, unsigned kp1, int npts) {
  int e = blockIdx.x * 256 + threadIdx.x;
  if (e >= npts) return;
  int b = e / PPB, r = e % PPB, n = r / NS, s = r % NS;
  float dx, dy, dz; pixel_dir(n, dx, dy, dz);
  float delta = (1.12f - 0.88f) / 11.0f;
  float u = jax_uniform(kp0, kp1, (unsigned)e, (unsigned)npts);
  float zval = 0.88f + (float)s * delta + (u - 0.5f) * (float)(0.24 / 11.0);
  zv[e] = zval;
  float px = dx * zval, py = dy * zval, pz = dz * zval;
  const float *M = c2w + b * 16;
  float m[12];
#pragma unroll
  for (int i = 0; i < 12; i++) m[i] = M[i];
  pts[e * 3 + 0] = m[0] * px + m[1] * py + m[2] * pz + m[3];
  pts[e * 3 + 1] = m[4] * px + m[5] * py + m[6] * pz + m[7];
  pts[e * 3 + 2] = m[8] * px + m[9] * py + m[10] * pz + m[11];
}

// ---------------- SIREN forward v6 -------------------------------------------
// 32 points/block, 64 threads = ONE wave. Thread (g=t&15, h=t>>4) owns
// dims {8g..8g+7} x points {8h..8h+7} (per-thread work identical to v5).
// Why: R7 counters showed OccupancyPercent 14% — with 32KB blocks the grid was
// 6 blocks/CU of work vs 5 resident -> a 5+1 generation tail at ~1 wave/SIMD.
// 16KB blocks pack 10 resident / 12 work (10+2), per-gen time halves, and
// 1-wave blocks decouple barriers (no inter-wave gang stall; __syncthreads on
// one wave is ~free). Dropped the R7 software pipeline: VGPR=84 proved the
// compiler collapsed it. Rev-domain v_sin kept.
#define INV2PI 0.15915494309189535f

__global__ __launch_bounds__(64, 2) void k_siren(const float *pts, const float *freqs,
                                               const float *phases,
                                               const float *fw, const float *fb,
                                               const float *hw, const float *hb,
                                               const float *ow, const float *ob,
                                               float *outp) {
  __shared__ __align__(16) float xl[128 * 32];   // 16 KB
  const int t = threadIdx.x;
  const int g = t & 15;        // dim group: dims 8g..8g+7
  const int h = t >> 4;        // point group: points 8h..8h+7 (h in 0..3)
  const int base = blockIdx.x * 32;
  const int b = base / PPB;

  const float *fqb = freqs + b * 768;
  const float *phb = phases + b * 768;

  // ---- first layer: sin(freq * (pts @ fw + fb) + phase) ----
  {
    float pt[24];
    const float4 *ps = (const float4 *)(pts + (size_t)(base + 8 * h) * 3);
#pragma unroll
    for (int i = 0; i < 6; i++) ((float4 *)pt)[i] = ps[i];
    float fqv[8], phv[8], w0v[8], w1v[8], w2v[8], biv[8];
#pragma unroll
    for (int u = 0; u < 2; u++) {
      ((float4 *)fqv)[u] = ((const float4 *)fqb)[2 * g + u];
      ((float4 *)phv)[u] = ((const float4 *)phb)[2 * g + u];
      ((float4 *)w0v)[u] = ((const float4 *)fw)[2 * g + u];
      ((float4 *)w1v)[u] = ((const float4 *)(fw + 128))[2 * g + u];
      ((float4 *)w2v)[u] = ((const float4 *)(fw + 256))[2 * g + u];
      ((float4 *)biv)[u] = ((const float4 *)fb)[2 * g + u];
    }
#pragma unroll
    for (int j = 0; j < 8; j++) {
      float fr = fqv[j] * INV2PI, pr = phv[j] * INV2PI;
      float4 v0, v1;
      v0.x = __builtin_amdgcn_sinf(fr * (pt[0] * w0v[j] + pt[1] * w1v[j] + pt[2] * w2v[j] + biv[j]) + pr);
      v0.y = __builtin_amdgcn_sinf(fr * (pt[3] * w0v[j] + pt[4] * w1v[j] + pt[5] * w2v[j] + biv[j]) + pr);
      v0.z = __builtin_amdgcn_sinf(fr * (pt[6] * w0v[j] + pt[7] * w1v[j] + pt[8] * w2v[j] + biv[j]) + pr);
      v0.w = __builtin_amdgcn_sinf(fr * (pt[9] * w0v[j] + pt[10] * w1v[j] + pt[11] * w2v[j] + biv[j]) + pr);
      v1.x = __builtin_amdgcn_sinf(fr * (pt[12] * w0v[j] + pt[13] * w1v[j] + pt[14] * w2v[j] + biv[j]) + pr);
      v1.y = __builtin_amdgcn_sinf(fr * (pt[15] * w0v[j] + pt[16] * w1v[j] + pt[17] * w2v[j] + biv[j]) + pr);
      v1.z = __builtin_amdgcn_sinf(fr * (pt[18] * w0v[j] + pt[19] * w1v[j] + pt[20] * w2v[j] + biv[j]) + pr);
      v1.w = __builtin_amdgcn_sinf(fr * (pt[21] * w0v[j] + pt[22] * w1v[j] + pt[23] * w2v[j] + biv[j]) + pr);
      int r = 8 * g + j;
      int swz = ((r >> 2) & 7) << 2;
      *((float4 *)&xl[r * 32 + ((8 * h) ^ swz)]) = v0;
      *((float4 *)&xl[r * 32 + ((8 * h + 4) ^ swz)]) = v1;
    }
  }
  __syncthreads();

  // ---- hidden layers ----
#pragma unroll 1
  for (int L = 1; L < 6; L++) {
    float fqv[8], phv[8], biv[8];
#pragma unroll
    for (int u = 0; u < 2; u++) {
      ((float4 *)fqv)[u] = ((const float4 *)(fqb + L * 128))[2 * g + u];
      ((float4 *)phv)[u] = ((const float4 *)(phb + L * 128))[2 * g + u];
      ((float4 *)biv)[u] = ((const float4 *)(hb + (L - 1) * 128))[2 * g + u];
    }
    const float4 *Wl = (const float4 *)(hw + (size_t)(L - 1) * 16384);
    float acc[8][8];
#pragma unroll
    for (int j = 0; j < 8; j++)
#pragma unroll
      for (int p = 0; p < 8; p++) acc[j][p] = biv[j];
#pragma unroll 2
    for (int k = 0; k < 128; k++) {
      float4 wa = Wl[k * 32 + 2 * g];
      float4 wb = Wl[k * 32 + 2 * g + 1];
      int swz = ((k >> 2) & 7) << 2;
      const float4 x0 = *((const float4 *)&xl[k * 32 + ((8 * h) ^ swz)]);
      const float4 x1 = *((const float4 *)&xl[k * 32 + ((8 * h + 4) ^ swz)]);
#define ACCJ(j, WT)                                                           \
      acc[j][0] += x0.x * (WT); acc[j][1] += x0.y * (WT);                     \
      acc[j][2] += x0.z * (WT); acc[j][3] += x0.w * (WT);                     \
      acc[j][4] += x1.x * (WT); acc[j][5] += x1.y * (WT);                     \
      acc[j][6] += x1.z * (WT); acc[j][7] += x1.w * (WT);
      ACCJ(0, wa.x) ACCJ(1, wa.y) ACCJ(2, wa.z) ACCJ(3, wa.w)
      ACCJ(4, wb.x) ACCJ(5, wb.y) ACCJ(6, wb.z) ACCJ(7, wb.w)
#undef ACCJ
    }
    __syncthreads();
#pragma unroll
    for (int j = 0; j < 8; j++) {
      float fr = fqv[j] * INV2PI, pr = phv[j] * INV2PI;
      float4 v0, v1;
      v0.x = __builtin_amdgcn_sinf(fr * acc[j][0] + pr);
      v0.y = __builtin_amdgcn_sinf(fr * acc[j][1] + pr);
      v0.z = __builtin_amdgcn_sinf(fr * acc[j][2] + pr);
      v0.w = __builtin_amdgcn_sinf(fr * acc[j][3] + pr);
      v1.x = __builtin_amdgcn_sinf(fr * acc[j][4] + pr);
      v1.y = __builtin_amdgcn_sinf(fr * acc[j][5] + pr);
      v1.z = __builtin_amdgcn_sinf(fr * acc[j][6] + pr);
      v1.w = __builtin_amdgcn_sinf(fr * acc[j][7] + pr);
      int r = 8 * g + j;
      int swz = ((r >> 2) & 7) << 2;
      *((float4 *)&xl[r * 32 + ((8 * h) ^ swz)]) = v0;
      *((float4 *)&xl[r * 32 + ((8 * h + 4) ^ swz)]) = v1;
    }
    __syncthreads();
  }

  // ---- output layer: thread -> (point p = t>>1, channel pair c2 = t&1) ----
  {
    int p = t >> 1, c2 = t & 1;
    const float2 *ow2 = (const float2 *)ow;
    float2 a = ((const float2 *)ob)[c2];
#pragma unroll 4
    for (int k = 0; k < 128; k++) {
      float x = xl[k * 32 + (p ^ (((k >> 2) & 7) << 2))];
      float2 wv = ow2[k * 2 + c2];
      a.x += x * wv.x;
      a.y += x * wv.y;
    }
    if (c2 == 0) {
      a.x = 1.0f / (1.0f + __expf(-a.x));
      a.y = 1.0f / (1.0f + __expf(-a.y));
    } else {
      a.x = 1.0f / (1.0f + __expf(-a.x));
    }
    *((float2 *)&outp[(size_t)(base + p) * 4 + 2 * c2]) = a;
  }
}

// ---------------- coarse weights -> sample_pdf -> fine points ----------------
__global__ __launch_bounds__(256) void k_pdf(const float *zv, const float *coutb,
                                             const float *c2w, float *fz, float *fpts,
                                             unsigned kq0, unsigned kq1, int nrays) {
  int ray = blockIdx.x * 256 + threadIdx.x;
  if (ray >= nrays) return;
  int b = ray / HW, n = ray % HW;
  float z[12];
#pragma unroll
  for (int s = 0; s < 12; s++) z[s] = zv[ray * 12 + s];
  float w[12]; float T = 1.0f;
#pragma unroll
  for (int s = 0; s < 12; s++) {
    float d = (s < 11) ? z[s + 1] - z[s] : 1e10f;
    float sg = coutb[(ray * 12 + s) * 4 + 3];
    float a = 1.0f - expf(-d * fmaxf(sg, 0.0f));
    w[s] = a * T;
    T *= 1.0f - a + 1e-10f;
  }
  float zmid[11];
#pragma unroll
  for (int i = 0; i < 11; i++) zmid[i] = 0.5f * (z[i] + z[i + 1]);
  float pw[10], sum = 0.0f;
#pragma unroll
  for (int i = 0; i < 10; i++) { pw[i] = w[i + 1] + 1e-5f; sum += pw[i]; }
  float cdf[11]; cdf[0] = 0.0f; float cacc = 0.0f;
#pragma unroll
  for (int i = 0; i < 10; i++) { cacc += pw[i] / sum; cdf[i + 1] = cacc; }

  const float *M = c2w + b * 16;
  float m[12];
#pragma unroll
  for (int i = 0; i < 12; i++) m[i] = M[i];
  float dx, dy, dz; pixel_dir(n, dx, dy, dz);
  float tdx = m[0] * dx + m[1] * dy + m[2] * dz;
  float tdy = m[4] * dx + m[5] * dy + m[6] * dz;
  float tdz = m[8] * dx + m[9] * dy + m[10] * dz;
  float ox = m[3], oy = m[7], oz = m[11];

#pragma unroll
  for (int t = 0; t < 12; t++) {
    float u = jax_uniform(kq0, kq1, (unsigned)(ray * 12 + t), (unsigned)(nrays * 12));
    int ind = 0;
#pragma unroll
    for (int i = 0; i < 11; i++) ind += (cdf[i] <= u) ? 1 : 0;  // searchsorted 'right'
    int below = ind - 1; below = below < 0 ? 0 : (below > 10 ? 10 : below);
    int above = ind > 10 ? 10 : ind;
    float cl = 0.f, ch = 0.f, blo = 0.f, bhi = 0.f;
#pragma unroll
    for (int i = 0; i < 11; i++) {
      if (i == below) { cl = cdf[i]; blo = zmid[i]; }
      if (i == above) { ch = cdf[i]; bhi = zmid[i]; }
    }
    float den = ch - cl; if (den < 1e-8f) den = 1.0f;
    float f = blo + (u - cl) / den * (bhi - blo);
    fz[ray * 12 + t] = f;
    fpts[(ray * 12 + t) * 3 + 0] = ox + tdx * f;
    fpts[(ray * 12 + t) * 3 + 1] = oy + tdy * f;
    fpts[(ray * 12 + t) * 3 + 2] = oz + tdz * f;
  }
}

// ---------------- merge (stable sort by z), final integration ----------------
__global__ __launch_bounds__(64) void k_final(const float *zv, const float *fz,
                                              const float *coutb, const float *foutb,
                                              float *outp, int B) {
  __shared__ float L[120 * 64];   // per-thread column: z[24], sig[24], rgb[3][24]
  __shared__ int inv[24 * 64];
  int t = threadIdx.x;
  int ray = blockIdx.x * 64 + t;
  int b = ray / HW, n = ray % HW;
#define SL(e) L[(e) * 64 + t]
  float zr[24];
#pragma unroll
  for (int s = 0; s < 12; s++) {
    float zfv = fz[ray * 12 + s], zcv = zv[ray * 12 + s];
    zr[s] = zfv; zr[12 + s] = zcv;   // concat order: fine first, then coarse
    SL(s) = zfv; SL(12 + s) = zcv;
    SL(24 + s)      = foutb[(ray * 12 + s) * 4 + 3];
    SL(24 + 12 + s) = coutb[(ray * 12 + s) * 4 + 3];
#pragma unroll
    for (int c = 0; c < 3; c++) {
      SL(48 + c * 24 + s)      = foutb[(ray * 12 + s) * 4 + c];
      SL(48 + c * 24 + 12 + s) = coutb[(ray * 12 + s) * 4 + c];
    }
  }
  // stable ranks (ties broken by original index) == JAX stable argsort
#pragma unroll
  for (int i = 0; i < 24; i++) {
    int rank = 0;
#pragma unroll
    for (int j = 0; j < 24; j++)
      rank += (zr[j] < zr[i] || (zr[j] == zr[i] && j < i)) ? 1 : 0;
    inv[rank * 64 + t] = i;
  }
  float Tacc = 1.0f, r0 = 0.f, r1 = 0.f, r2 = 0.f, df = 0.f;
  int icur = inv[0 * 64 + t];
  float zcur = SL(icur);
  for (int r = 0; r < 24; r++) {
    int inext = 0; float znext = 0.f;
    if (r < 23) { inext = inv[(r + 1) * 64 + t]; znext = SL(inext); }
    float d = (r < 23) ? znext - zcur : 1e10f;
    float sg = SL(24 + icur);
    float a = 1.0f - expf(-d * fmaxf(sg, 0.0f));
    float wt = a * Tacc;
    Tacc *= 1.0f - a + 1e-10f;
    r0 += wt * SL(48 + icur);
    r1 += wt * SL(48 + 24 + icur);
    r2 += wt * SL(48 + 48 + icur);
    df += wt * zcur;
    icur = inext; zcur = znext;
  }
#undef SL
  int pi = n >> 6, pj = n & 63;
  float x = -1.0f + (float)pj * (2.0f / 63.0f);
  float y =  1.0f - (float)pi * (2.0f / 63.0f);
  float zc = -1.0f / tanf(0.10471975511965978f);
  float invn = 1.0f / sqrtf(x * x + y * y + zc * zc);
  float mdz = -zc * invn;  // -rays_d.z (positive)
  outp[(b * 3 + 0) * HW + n] = r0 * 2.0f - 1.0f;
  outp[(b * 3 + 1) * HW + n] = r1 * 2.0f - 1.0f;
  outp[(b * 3 + 2) * HW + n] = r2 * 2.0f - 1.0f;
  outp[B * 3 * HW + ray] = df * mdz;
}

extern "C" void kernel_launch(void *const *d_in, const int *in_sizes, int n_in,
                              void *d_out, int out_size, void *d_ws, size_t ws_size,
                              hipStream_t stream) {
  const float *z   = (const float *)d_in[0];
  const float *c2w = (const float *)d_in[1];
  const float *mw0 = (const float *)d_in[2];
  const float *mb0 = (const float *)d_in[3];
  const float *mw1 = (const float *)d_in[4];
  const float *mb1 = (const float *)d_in[5];
  const float *mw2 = (const float *)d_in[6];
  const float *mb2 = (const float *)d_in[7];
  const float *fw  = (const float *)d_in[8];
  const float *fb  = (const float *)d_in[9];
  const float *hw  = (const float *)d_in[10];
  const float *hb  = (const float *)d_in[11];
  const float *ow  = (const float *)d_in[12];
  const float *ob  = (const float *)d_in[13];
  int B = in_sizes[0] / 256;
  int npts = B * PPB;
  int nrays = B * HW;

  float *ws     = (float *)d_ws;
  float *freqs  = ws;
  float *phases = freqs + (size_t)B * 768;
  float *zv     = phases + (size_t)B * 768;
  float *cpts   = zv + npts;
  float *coutb  = cpts + (size_t)npts * 3;
  float *fzv    = coutb + (size_t)npts * 4;
  float *fpts   = fzv + npts;
  float *foutb  = fpts + (size_t)npts * 3;

  // key(42) = [0,42]; split -> k_pert, k_pdf
  unsigned kp0, kp1, kq0, kq1;
#if JAX_PARTITIONABLE
  { unsigned o0, o1;
    tf2x32(0u, 42u, 0u, 0u, o0, o1); kp0 = o0; kp1 = o1;
    tf2x32(0u, 42u, 0u, 1u, o0, o1); kq0 = o0; kq1 = o1; }
#else
  { unsigned a0, a1, c0, c1;
    tf2x32(0u, 42u, 0u, 2u, a0, a1);
    tf2x32(0u, 42u, 1u, 3u, c0, c1);
    kp0 = a0; kp1 = c0; kq0 = a1; kq1 = c1; }
#endif

  k_map<<<B, 256, 0, stream>>>(z, mw0, mb0, mw1, mb1, mw2, mb2, freqs, phases);
  k_rays<<<(npts + 255) / 256, 256, 0, stream>>>(c2w, zv, cpts, kp0, kp1, npts);
  k_siren<<<npts / 32, 64, 0, stream>>>(cpts, freqs, phases, fw, fb, hw, hb, ow, ob, coutb);
  k_pdf<<<(nrays + 255) / 256, 256, 0, stream>>>(zv, coutb, c2w, fzv, fpts, kq0, kq1, nrays);
  k_siren<<<npts / 32, 64, 0, stream>>>(fpts, freqs, phases, fw, fb, hw, hb, ow, ob, foutb);
  k_final<<<nrays / 64, 64, 0, stream>>>(zv, fzv, coutb, foutb, (float *)d_out, B);
}

// Round 9
// 609.379 us; speedup vs baseline: 1.8506x; 1.0738x over previous
//
#include <hip/hip_runtime.h>
#include <hip/hip_bf16.h>

// ---- JAX PRNG variant switches (verified passing in R2) ----
#define JAX_PARTITIONABLE 1
#define PART_MODE 2   // bits = o0 ^ o1

#define HW 4096      // 64*64 pixels
#define NS 12        // num_steps
#define PPB 49152    // HW*NS points per batch element

__host__ __device__ __forceinline__ void tf2x32(unsigned k0, unsigned k1,
                                                unsigned x0, unsigned x1,
                                                unsigned &o0, unsigned &o1) {
  unsigned ks2 = k0 ^ k1 ^ 0x1BD11BDAu;
  unsigned v0 = x0 + k0, v1 = x1 + k1;
#define TFR(r) do { v0 += v1; v1 = (v1 << (r)) | (v1 >> (32 - (r))); v1 ^= v0; } while (0)
  TFR(13); TFR(15); TFR(26); TFR(6);   v0 += k1;  v1 += ks2 + 1u;
  TFR(17); TFR(29); TFR(16); TFR(24);  v0 += ks2; v1 += k0 + 2u;
  TFR(13); TFR(15); TFR(26); TFR(6);   v0 += k0;  v1 += k1 + 3u;
  TFR(17); TFR(29); TFR(16); TFR(24);  v0 += k1;  v1 += ks2 + 4u;
  TFR(13); TFR(15); TFR(26); TFR(6);   v0 += ks2; v1 += k0 + 5u;
#undef TFR
  o0 = v0; o1 = v1;
}

__device__ __forceinline__ float jax_uniform(unsigned k0, unsigned k1,
                                             unsigned idx, unsigned total) {
  unsigned o0, o1, bits;
#if JAX_PARTITIONABLE
  tf2x32(k0, k1, 0u, idx, o0, o1);
#if PART_MODE == 0
  bits = o0;
#elif PART_MODE == 1
  bits = o1;
#else
  bits = o0 ^ o1;
#endif
#else
  unsigned half = total >> 1;
  if (idx < half) { tf2x32(k0, k1, idx, idx + half, o0, o1); bits = o0; }
  else            { tf2x32(k0, k1, idx - half, idx, o0, o1); bits = o1; }
#endif
  return __uint_as_float(0x3f800000u | (bits >> 9)) - 1.0f;
}

__device__ __forceinline__ void pixel_dir(int n, float &dx, float &dy, float &dz) {
  int pi = n >> 6, pj = n & 63;
  float x = -1.0f + (float)pj * (2.0f / 63.0f);
  float y =  1.0f - (float)pi * (2.0f / 63.0f);
  float zc = -1.0f / tanf(0.10471975511965978f);  // deg2rad(12)/2
  float inv = 1.0f / sqrtf(x * x + y * y + zc * zc);
  dx = x * inv; dy = y * inv; dz = zc * inv;
}

// ---------------- mapping network: z(256) -> freqs/phases (768 each) ---------
__global__ __launch_bounds__(256) void k_map(const float *z, const float *w0, const float *b0,
                                             const float *w1, const float *b1,
                                             const float *w2, const float *b2,
                                             float *freqs, float *phases) {
  __shared__ float zl[256], h1[256], h2[256];
  int b = blockIdx.x, t = threadIdx.x;
  zl[t] = z[b * 256 + t];
  __syncthreads();
  float acc = b0[t];
  for (int k = 0; k < 256; k++) acc += zl[k] * w0[k * 256 + t];
  h1[t] = (acc >= 0.0f) ? acc : 0.2f * acc;
  __syncthreads();
  acc = b1[t];
  for (int k = 0; k < 256; k++) acc += h1[k] * w1[k * 256 + t];
  h2[t] = (acc >= 0.0f) ? acc : 0.2f * acc;
  __syncthreads();
  float a6[6];
#pragma unroll
  for (int m = 0; m < 6; m++) a6[m] = b2[t + m * 256];
  for (int k = 0; k < 256; k++) {
    float h = h2[k];
#pragma unroll
    for (int m = 0; m < 6; m++) a6[m] += h * w2[k * 1536 + t + m * 256];
  }
#pragma unroll
  for (int m = 0; m < 6; m++) {
    int o = t + m * 256;
    if (o < 768) freqs[b * 768 + o] = a6[m] * 15.0f + 30.0f;
    else         phases[b * 768 + (o - 768)] = a6[m];
  }
}

// ---------------- coarse rays: perturbed z + transformed points --------------
__global__ __launch_bounds__(256) void k_rays(const float *c2w, float *zv, float *pts,
                                              unsigned kp0, unsigned kp1, int npts) {
  int e = blockIdx.x * 256 + threadIdx.x;
  if (e >= npts) return;
  int b = e / PPB, r = e % PPB, n = r / NS, s = r % NS;
  float dx, dy, dz; pixel_dir(n, dx, dy, dz);
  float delta = (1.12f - 0.88f) / 11.0f;
  float u = jax_uniform(kp0, kp1, (unsigned)e, (unsigned)npts);
  float zval = 0.88f + (float)s * delta + (u - 0.5f) * (float)(0.24 / 11.0);
  zv[e] = zval;
  float px = dx * zval, py = dy * zval, pz = dz * zval;
  const float *M = c2w + b * 16;
  float m[12];
#pragma unroll
  for (int i = 0; i < 12; i++) m[i] = M[i];
  pts[e * 3 + 0] = m[0] * px + m[1] * py + m[2] * pz + m[3];
  pts[e * 3 + 1] = m[4] * px + m[5] * py + m[6] * pz + m[7];
  pts[e * 3 + 2] = m[8] * px + m[9] * py + m[10] * pz + m[11];
}

// ---------------- SIREN forward v7 -------------------------------------------
// 32 points/block, 128 threads = 2 waves SPLITTING the k-reduction.
// R8 counters: OccupancyPercent 18% == (10 resident + 2 tail)/2 generations of
// identical-T blocks (12 blocks/CU work vs 10 resident at 16KB LDS). v7 halves
// per-block T: wave w accumulates k in [64w,64w+64) (wave1 from 0, wave0 from
// bias); exchange via xl in-place (wave1 stores partials at the output slots,
// wave0 adds+sin+rewrites). Wall 2T -> ~T; gen1 now 20 waves/CU (5/SIMD).
// First layer split by dims (row = 8g+4w+j); output layer 1 chan x 1 pt/thread.
#define INV2PI 0.15915494309189535f

__global__ __launch_bounds__(128, 2) void k_siren(const float *pts, const float *freqs,
                                               const float *phases,
                                               const float *fw, const float *fb,
                                               const float *hw, const float *hb,
                                               const float *ow, const float *ob,
                                               float *outp) {
  __shared__ __align__(16) float xl[128 * 32];   // 16 KB
  const int t = threadIdx.x;
  const int w = t >> 6;        // wave id 0/1
  const int tt = t & 63;
  const int g = tt & 15;       // dim group: dims 8g..8g+7
  const int h = tt >> 4;       // point group: points 8h..8h+7 (h in 0..3)
  const int base = blockIdx.x * 32;
  const int b = base / PPB;

  const float *fqb = freqs + b * 768;
  const float *phb = phases + b * 768;

  // ---- first layer: rows 8g+4w..8g+4w+3 (chunk c4=2g+w), points 8h..8h+7 ----
  {
    float pt[24];
    const float4 *ps = (const float4 *)(pts + (size_t)(base + 8 * h) * 3);
#pragma unroll
    for (int i = 0; i < 6; i++) ((float4 *)pt)[i] = ps[i];
    const int c4 = 2 * g + w;
    float fqv[4], phv[4], w0v[4], w1v[4], w2v[4], biv[4];
    ((float4 *)fqv)[0] = ((const float4 *)fqb)[c4];
    ((float4 *)phv)[0] = ((const float4 *)phb)[c4];
    ((float4 *)w0v)[0] = ((const float4 *)fw)[c4];
    ((float4 *)w1v)[0] = ((const float4 *)(fw + 128))[c4];
    ((float4 *)w2v)[0] = ((const float4 *)(fw + 256))[c4];
    ((float4 *)biv)[0] = ((const float4 *)fb)[c4];
#pragma unroll
    for (int j = 0; j < 4; j++) {
      float fr = fqv[j] * INV2PI, pr = phv[j] * INV2PI;
      float4 v0, v1;
      v0.x = __builtin_amdgcn_sinf(fr * (pt[0] * w0v[j] + pt[1] * w1v[j] + pt[2] * w2v[j] + biv[j]) + pr);
      v0.y = __builtin_amdgcn_sinf(fr * (pt[3] * w0v[j] + pt[4] * w1v[j] + pt[5] * w2v[j] + biv[j]) + pr);
      v0.z = __builtin_amdgcn_sinf(fr * (pt[6] * w0v[j] + pt[7] * w1v[j] + pt[8] * w2v[j] + biv[j]) + pr);
      v0.w = __builtin_amdgcn_sinf(fr * (pt[9] * w0v[j] + pt[10] * w1v[j] + pt[11] * w2v[j] + biv[j]) + pr);
      v1.x = __builtin_amdgcn_sinf(fr * (pt[12] * w0v[j] + pt[13] * w1v[j] + pt[14] * w2v[j] + biv[j]) + pr);
      v1.y = __builtin_amdgcn_sinf(fr * (pt[15] * w0v[j] + pt[16] * w1v[j] + pt[17] * w2v[j] + biv[j]) + pr);
      v1.z = __builtin_amdgcn_sinf(fr * (pt[18] * w0v[j] + pt[19] * w1v[j] + pt[20] * w2v[j] + biv[j]) + pr);
      v1.w = __builtin_amdgcn_sinf(fr * (pt[21] * w0v[j] + pt[22] * w1v[j] + pt[23] * w2v[j] + biv[j]) + pr);
      int r = 8 * g + 4 * w + j;              // r>>2 == c4
      int swz = (c4 & 7) << 2;
      *((float4 *)&xl[r * 32 + ((8 * h) ^ swz)]) = v0;
      *((float4 *)&xl[r * 32 + ((8 * h + 4) ^ swz)]) = v1;
    }
  }
  __syncthreads();

  // ---- hidden layers: 2-wave k-split + in-place exchange ----
#pragma unroll 1
  for (int L = 1; L < 6; L++) {
    float fqv[8], phv[8], biv[8];
#pragma unroll
    for (int u = 0; u < 2; u++) {
      ((float4 *)fqv)[u] = ((const float4 *)(fqb + L * 128))[2 * g + u];
      ((float4 *)phv)[u] = ((const float4 *)(phb + L * 128))[2 * g + u];
      ((float4 *)biv)[u] = ((const float4 *)(hb + (L - 1) * 128))[2 * g + u];
    }
    const float4 *Wl = (const float4 *)(hw + (size_t)(L - 1) * 16384);
    float acc[8][8];
#pragma unroll
    for (int j = 0; j < 8; j++)
#pragma unroll
      for (int p = 0; p < 8; p++) acc[j][p] = (w == 0) ? biv[j] : 0.0f;
    const int k0 = 64 * w;
#pragma unroll 2
    for (int kk = 0; kk < 64; kk++) {
      int k = k0 + kk;
      float4 wa = Wl[k * 32 + 2 * g];
      float4 wb = Wl[k * 32 + 2 * g + 1];
      int swz = ((k >> 2) & 7) << 2;
      const float4 x0 = *((const float4 *)&xl[k * 32 + ((8 * h) ^ swz)]);
      const float4 x1 = *((const float4 *)&xl[k * 32 + ((8 * h + 4) ^ swz)]);
#define ACCJ(j, WT)                                                           \
      acc[j][0] += x0.x * (WT); acc[j][1] += x0.y * (WT);                     \
      acc[j][2] += x0.z * (WT); acc[j][3] += x0.w * (WT);                     \
      acc[j][4] += x1.x * (WT); acc[j][5] += x1.y * (WT);                     \
      acc[j][6] += x1.z * (WT); acc[j][7] += x1.w * (WT);
      ACCJ(0, wa.x) ACCJ(1, wa.y) ACCJ(2, wa.z) ACCJ(3, wa.w)
      ACCJ(4, wb.x) ACCJ(5, wb.y) ACCJ(6, wb.z) ACCJ(7, wb.w)
#undef ACCJ
    }
    __syncthreads();
    // wave1 parks its partial sums at the exact output slots
    if (w == 1) {
#pragma unroll
      for (int j = 0; j < 8; j++) {
        int r = 8 * g + j;
        int swz = ((r >> 2) & 7) << 2;
        float4 v0, v1;
        v0.x = acc[j][0]; v0.y = acc[j][1]; v0.z = acc[j][2]; v0.w = acc[j][3];
        v1.x = acc[j][4]; v1.y = acc[j][5]; v1.z = acc[j][6]; v1.w = acc[j][7];
        *((float4 *)&xl[r * 32 + ((8 * h) ^ swz)]) = v0;
        *((float4 *)&xl[r * 32 + ((8 * h + 4) ^ swz)]) = v1;
      }
    }
    __syncthreads();
    // wave0 adds, applies sin, rewrites in place
    if (w == 0) {
#pragma unroll
      for (int j = 0; j < 8; j++) {
        int r = 8 * g + j;
        int swz = ((r >> 2) & 7) << 2;
        float4 *a0 = (float4 *)&xl[r * 32 + ((8 * h) ^ swz)];
        float4 *a1 = (float4 *)&xl[r * 32 + ((8 * h + 4) ^ swz)];
        float4 p0 = *a0, p1 = *a1;
        float fr = fqv[j] * INV2PI, pr = phv[j] * INV2PI;
        float4 v0, v1;
        v0.x = __builtin_amdgcn_sinf(fr * (acc[j][0] + p0.x) + pr);
        v0.y = __builtin_amdgcn_sinf(fr * (acc[j][1] + p0.y) + pr);
        v0.z = __builtin_amdgcn_sinf(fr * (acc[j][2] + p0.z) + pr);
        v0.w = __builtin_amdgcn_sinf(fr * (acc[j][3] + p0.w) + pr);
        v1.x = __builtin_amdgcn_sinf(fr * (acc[j][4] + p1.x) + pr);
        v1.y = __builtin_amdgcn_sinf(fr * (acc[j][5] + p1.y) + pr);
        v1.z = __builtin_amdgcn_sinf(fr * (acc[j][6] + p1.z) + pr);
        v1.w = __builtin_amdgcn_sinf(fr * (acc[j][7] + p1.w) + pr);
        *a0 = v0;
        *a1 = v1;
      }
    }
    __syncthreads();
  }

  // ---- output layer: thread -> (point p = t>>2, channel c = t&3) ----
  {
    int p = t >> 2, c = t & 3;
    float a = ob[c];
#pragma unroll 4
    for (int k = 0; k < 128; k++) {
      float x = xl[k * 32 + (p ^ (((k >> 2) & 7) << 2))];
      a += x * ow[k * 4 + c];
    }
    if (c < 3) a = 1.0f / (1.0f + __expf(-a));
    outp[(size_t)base * 4 + t] = a;   // == outp[(base+p)*4+c], fully coalesced
  }
}

// ---------------- coarse weights -> sample_pdf -> fine points ----------------
__global__ __launch_bounds__(256) void k_pdf(const float *zv, const float *coutb,
                                             const float *c2w, float *fz, float *fpts,
                                             unsigned kq0, unsigned kq1, int nrays) {
  int ray = blockIdx.x * 256 + threadIdx.x;
  if (ray >= nrays) return;
  int b = ray / HW, n = ray % HW;
  float z[12];
#pragma unroll
  for (int s = 0; s < 12; s++) z[s] = zv[ray * 12 + s];
  float w[12]; float T = 1.0f;
#pragma unroll
  for (int s = 0; s < 12; s++) {
    float d = (s < 11) ? z[s + 1] - z[s] : 1e10f;
    float sg = coutb[(ray * 12 + s) * 4 + 3];
    float a = 1.0f - expf(-d * fmaxf(sg, 0.0f));
    w[s] = a * T;
    T *= 1.0f - a + 1e-10f;
  }
  float zmid[11];
#pragma unroll
  for (int i = 0; i < 11; i++) zmid[i] = 0.5f * (z[i] + z[i + 1]);
  float pw[10], sum = 0.0f;
#pragma unroll
  for (int i = 0; i < 10; i++) { pw[i] = w[i + 1] + 1e-5f; sum += pw[i]; }
  float cdf[11]; cdf[0] = 0.0f; float cacc = 0.0f;
#pragma unroll
  for (int i = 0; i < 10; i++) { cacc += pw[i] / sum; cdf[i + 1] = cacc; }

  const float *M = c2w + b * 16;
  float m[12];
#pragma unroll
  for (int i = 0; i < 12; i++) m[i] = M[i];
  float dx, dy, dz; pixel_dir(n, dx, dy, dz);
  float tdx = m[0] * dx + m[1] * dy + m[2] * dz;
  float tdy = m[4] * dx + m[5] * dy + m[6] * dz;
  float tdz = m[8] * dx + m[9] * dy + m[10] * dz;
  float ox = m[3], oy = m[7], oz = m[11];

#pragma unroll
  for (int t = 0; t < 12; t++) {
    float u = jax_uniform(kq0, kq1, (unsigned)(ray * 12 + t), (unsigned)(nrays * 12));
    int ind = 0;
#pragma unroll
    for (int i = 0; i < 11; i++) ind += (cdf[i] <= u) ? 1 : 0;  // searchsorted 'right'
    int below = ind - 1; below = below < 0 ? 0 : (below > 10 ? 10 : below);
    int above = ind > 10 ? 10 : ind;
    float cl = 0.f, ch = 0.f, blo = 0.f, bhi = 0.f;
#pragma unroll
    for (int i = 0; i < 11; i++) {
      if (i == below) { cl = cdf[i]; blo = zmid[i]; }
      if (i == above) { ch = cdf[i]; bhi = zmid[i]; }
    }
    float den = ch - cl; if (den < 1e-8f) den = 1.0f;
    float f = blo + (u - cl) / den * (bhi - blo);
    fz[ray * 12 + t] = f;
    fpts[(ray * 12 + t) * 3 + 0] = ox + tdx * f;
    fpts[(ray * 12 + t) * 3 + 1] = oy + tdy * f;
    fpts[(ray * 12 + t) * 3 + 2] = oz + tdz * f;
  }
}

// ---------------- merge (stable sort by z), final integration ----------------
__global__ __launch_bounds__(64) void k_final(const float *zv, const float *fz,
                                              const float *coutb, const float *foutb,
                                              float *outp, int B) {
  __shared__ float L[120 * 64];   // per-thread column: z[24], sig[24], rgb[3][24]
  __shared__ int inv[24 * 64];
  int t = threadIdx.x;
  int ray = blockIdx.x * 64 + t;
  int b = ray / HW, n = ray % HW;
#define SL(e) L[(e) * 64 + t]
  float zr[24];
#pragma unroll
  for (int s = 0; s < 12; s++) {
    float zfv = fz[ray * 12 + s], zcv = zv[ray * 12 + s];
    zr[s] = zfv; zr[12 + s] = zcv;   // concat order: fine first, then coarse
    SL(s) = zfv; SL(12 + s) = zcv;
    SL(24 + s)      = foutb[(ray * 12 + s) * 4 + 3];
    SL(24 + 12 + s) = coutb[(ray * 12 + s) * 4 + 3];
#pragma unroll
    for (int c = 0; c < 3; c++) {
      SL(48 + c * 24 + s)      = foutb[(ray * 12 + s) * 4 + c];
      SL(48 + c * 24 + 12 + s) = coutb[(ray * 12 + s) * 4 + c];
    }
  }
  // stable ranks (ties broken by original index) == JAX stable argsort
#pragma unroll
  for (int i = 0; i < 24; i++) {
    int rank = 0;
#pragma unroll
    for (int j = 0; j < 24; j++)
      rank += (zr[j] < zr[i] || (zr[j] == zr[i] && j < i)) ? 1 : 0;
    inv[rank * 64 + t] = i;
  }
  float Tacc = 1.0f, r0 = 0.f, r1 = 0.f, r2 = 0.f, df = 0.f;
  int icur = inv[0 * 64 + t];
  float zcur = SL(icur);
  for (int r = 0; r < 24; r++) {
    int inext = 0; float znext = 0.f;
    if (r < 23) { inext = inv[(r + 1) * 64 + t]; znext = SL(inext); }
    float d = (r < 23) ? znext - zcur : 1e10f;
    float sg = SL(24 + icur);
    float a = 1.0f - expf(-d * fmaxf(sg, 0.0f));
    float wt = a * Tacc;
    Tacc *= 1.0f - a + 1e-10f;
    r0 += wt * SL(48 + icur);
    r1 += wt * SL(48 + 24 + icur);
    r2 += wt * SL(48 + 48 + icur);
    df += wt * zcur;
    icur = inext; zcur = znext;
  }
#undef SL
  int pi = n >> 6, pj = n & 63;
  float x = -1.0f + (float)pj * (2.0f / 63.0f);
  float y =  1.0f - (float)pi * (2.0f / 63.0f);
  float zc = -1.0f / tanf(0.10471975511965978f);
  float invn = 1.0f / sqrtf(x * x + y * y + zc * zc);
  float mdz = -zc * invn;  // -rays_d.z (positive)
  outp[(b * 3 + 0) * HW + n] = r0 * 2.0f - 1.0f;
  outp[(b * 3 + 1) * HW + n] = r1 * 2.0f - 1.0f;
  outp[(b * 3 + 2) * HW + n] = r2 * 2.0f - 1.0f;
  outp[B * 3 * HW + ray] = df * mdz;
}

extern "C" void kernel_launch(void *const *d_in, const int *in_sizes, int n_in,
                              void *d_out, int out_size, void *d_ws, size_t ws_size,
                              hipStream_t stream) {
  const float *z   = (const float *)d_in[0];
  const float *c2w = (const float *)d_in[1];
  const float *mw0 = (const float *)d_in[2];
  const float *mb0 = (const float *)d_in[3];
  const float *mw1 = (const float *)d_in[4];
  const float *mb1 = (const float *)d_in[5];
  const float *mw2 = (const float *)d_in[6];
  const float *mb2 = (const float *)d_in[7];
  const float *fw  = (const float *)d_in[8];
  const float *fb  = (const float *)d_in[9];
  const float *hw  = (const float *)d_in[10];
  const float *hb  = (const float *)d_in[11];
  const float *ow  = (const float *)d_in[12];
  const float *ob  = (const float *)d_in[13];
  int B = in_sizes[0] / 256;
  int npts = B * PPB;
  int nrays = B * HW;

  float *ws     = (float *)d_ws;
  float *freqs  = ws;
  float *phases = freqs + (size_t)B * 768;
  float *zv     = phases + (size_t)B * 768;
  float *cpts   = zv + npts;
  float *coutb  = cpts + (size_t)npts * 3;
  float *fzv    = coutb + (size_t)npts * 4;
  float *fpts   = fzv + npts;
  float *foutb  = fpts + (size_t)npts * 3;

  // key(42) = [0,42]; split -> k_pert, k_pdf
  unsigned kp0, kp1, kq0, kq1;
#if JAX_PARTITIONABLE
  { unsigned o0, o1;
    tf2x32(0u, 42u, 0u, 0u, o0, o1); kp0 = o0; kp1 = o1;
    tf2x32(0u, 42u, 0u, 1u, o0, o1); kq0 = o0; kq1 = o1; }
#else
  { unsigned a0, a1, c0, c1;
    tf2x32(0u, 42u, 0u, 2u, a0, a1);
    tf2x32(0u, 42u, 1u, 3u, c0, c1);
    kp0 = a0; kp1 = c0; kq0 = a1; kq1 = c1; }
#endif

  k_map<<<B, 256, 0, stream>>>(z, mw0, mb0, mw1, mb1, mw2, mb2, freqs, phases);
  k_rays<<<(npts + 255) / 256, 256, 0, stream>>>(c2w, zv, cpts, kp0, kp1, npts);
  k_siren<<<npts / 32, 128, 0, stream>>>(cpts, freqs, phases, fw, fb, hw, hb, ow, ob, coutb);
  k_pdf<<<(nrays + 255) / 256, 256, 0, stream>>>(zv, coutb, c2w, fzv, fpts, kq0, kq1, nrays);
  k_siren<<<npts / 32, 128, 0, stream>>>(fpts, freqs, phases, fw, fb, hw, hb, ow, ob, foutb);
  k_final<<<nrays / 64, 64, 0, stream>>>(zv, fzv, coutb, foutb, (float *)d_out, B);
}

// Round 10
// 341.964 us; speedup vs baseline: 3.2978x; 1.7820x over previous
//
#include <hip/hip_runtime.h>
#include <hip/hip_bf16.h>

// ---- JAX PRNG variant switches (verified passing in R2) ----
#define JAX_PARTITIONABLE 1
#define PART_MODE 2   // bits = o0 ^ o1

#define HW 4096      // 64*64 pixels
#define NS 12        // num_steps
#define PPB 49152    // HW*NS points per batch element

typedef __attribute__((ext_vector_type(8))) short short8;
typedef __attribute__((ext_vector_type(4))) float f32x4;

__host__ __device__ __forceinline__ void tf2x32(unsigned k0, unsigned k1,
                                                unsigned x0, unsigned x1,
                                                unsigned &o0, unsigned &o1) {
  unsigned ks2 = k0 ^ k1 ^ 0x1BD11BDAu;
  unsigned v0 = x0 + k0, v1 = x1 + k1;
#define TFR(r) do { v0 += v1; v1 = (v1 << (r)) | (v1 >> (32 - (r))); v1 ^= v0; } while (0)
  TFR(13); TFR(15); TFR(26); TFR(6);   v0 += k1;  v1 += ks2 + 1u;
  TFR(17); TFR(29); TFR(16); TFR(24);  v0 += ks2; v1 += k0 + 2u;
  TFR(13); TFR(15); TFR(26); TFR(6);   v0 += k0;  v1 += k1 + 3u;
  TFR(17); TFR(29); TFR(16); TFR(24);  v0 += k1;  v1 += ks2 + 4u;
  TFR(13); TFR(15); TFR(26); TFR(6);   v0 += ks2; v1 += k0 + 5u;
#undef TFR
  o0 = v0; o1 = v1;
}

__device__ __forceinline__ float jax_uniform(unsigned k0, unsigned k1,
                                             unsigned idx, unsigned total) {
  unsigned o0, o1, bits;
#if JAX_PARTITIONABLE
  tf2x32(k0, k1, 0u, idx, o0, o1);
#if PART_MODE == 0
  bits = o0;
#elif PART_MODE == 1
  bits = o1;
#else
  bits = o0 ^ o1;
#endif
#else
  unsigned half = total >> 1;
  if (idx < half) { tf2x32(k0, k1, idx, idx + half, o0, o1); bits = o0; }
  else            { tf2x32(k0, k1, idx - half, idx, o0, o1); bits = o1; }
#endif
  return __uint_as_float(0x3f800000u | (bits >> 9)) - 1.0f;
}

__device__ __forceinline__ void pixel_dir(int n, float &dx, float &dy, float &dz) {
  int pi = n >> 6, pj = n & 63;
  float x = -1.0f + (float)pj * (2.0f / 63.0f);
  float y =  1.0f - (float)pi * (2.0f / 63.0f);
  float zc = -1.0f / tanf(0.10471975511965978f);  // deg2rad(12)/2
  float inv = 1.0f / sqrtf(x * x + y * y + zc * zc);
  dx = x * inv; dy = y * inv; dz = zc * inv;
}

// ---------------- mapping network: z(256) -> freqs/phases (768 each) ---------
__global__ __launch_bounds__(256) void k_map(const float *z, const float *w0, const float *b0,
                                             const float *w1, const float *b1,
                                             const float *w2, const float *b2,
                                             float *freqs, float *phases) {
  __shared__ float zl[256], h1[256], h2[256];
  int b = blockIdx.x, t = threadIdx.x;
  zl[t] = z[b * 256 + t];
  __syncthreads();
  float acc = b0[t];
  for (int k = 0; k < 256; k++) acc += zl[k] * w0[k * 256 + t];
  h1[t] = (acc >= 0.0f) ? acc : 0.2f * acc;
  __syncthreads();
  acc = b1[t];
  for (int k = 0; k < 256; k++) acc += h1[k] * w1[k * 256 + t];
  h2[t] = (acc >= 0.0f) ? acc : 0.2f * acc;
  __syncthreads();
  float a6[6];
#pragma unroll
  for (int m = 0; m < 6; m++) a6[m] = b2[t + m * 256];
  for (int k = 0; k < 256; k++) {
    float h = h2[k];
#pragma unroll
    for (int m = 0; m < 6; m++) a6[m] += h * w2[k * 1536 + t + m * 256];
  }
#pragma unroll
  for (int m = 0; m < 6; m++) {
    int o = t + m * 256;
    if (o < 768) freqs[b * 768 + o] = a6[m] * 15.0f + 30.0f;
    else         phases[b * 768 + (o - 768)] = a6[m];
  }
}

// ---------------- coarse rays: perturbed z + transformed points --------------
__global__ __launch_bounds__(256) void k_rays(const float *c2w, float *zv, float *pts,
                                              unsigned kp0, unsigned kp1, int npts) {
  int e = blockIdx.x * 256 + threadIdx.x;
  if (e >= npts) return;
  int b = e / PPB, r = e % PPB, n = r / NS, s = r % NS;
  float dx, dy, dz; pixel_dir(n, dx, dy, dz);
  float delta = (1.12f - 0.88f) / 11.0f;
  float u = jax_uniform(kp0, kp1, (unsigned)e, (unsigned)npts);
  float zval = 0.88f + (float)s * delta + (u - 0.5f) * (float)(0.24 / 11.0);
  zv[e] = zval;
  float px = dx * zval, py = dy * zval, pz = dz * zval;
  const float *M = c2w + b * 16;
  float m[12];
#pragma unroll
  for (int i = 0; i < 12; i++) m[i] = M[i];
  pts[e * 3 + 0] = m[0] * px + m[1] * py + m[2] * pz + m[3];
  pts[e * 3 + 1] = m[4] * px + m[5] * py + m[6] * pz + m[7];
  pts[e * 3 + 2] = m[8] * px + m[9] * py + m[10] * pz + m[11];
}

// ---------------- weight prep: hi/lo bf16 split in MFMA A-fragment order -----
// A = hid_w^T per layer: A[j][k] = hw[L][k][j]. Fragment for mfma_16x16x32:
// lane holds A[m=lane&15][k = (lane>>4)*8 + i], i=0..7. Chunk = (L*8+jt)*4+kb.
// Truncation split: hi = topbits(w); lo = bf16(w - hi). Also owT[c][k] transpose.
__global__ __launch_bounds__(256) void k_prep(const float *hw, const float *ow,
                                              unsigned short *Whi, unsigned short *Wlo,
                                              float *owT) {
  int tid = blockIdx.x * 256 + threadIdx.x;
  if (tid < 10240) {
    int lane = tid & 63;
    int chunk = tid >> 6;          // (L*8+jt)*4+kb, L=0..4
    int kb = chunk & 3;
    int jt = (chunk >> 2) & 7;
    int L = chunk >> 5;
    int m = lane & 15, quad = lane >> 4;
    int j = jt * 16 + m;
    int k0 = kb * 32 + quad * 8;
    size_t off = (size_t)chunk * 512 + lane * 8;
#pragma unroll
    for (int i = 0; i < 8; i++) {
      float wv = hw[((size_t)L * 128 + k0 + i) * 128 + j];
      unsigned u = __float_as_uint(wv);
      Whi[off + i] = (unsigned short)(u >> 16);
      float r = wv - __uint_as_float(u & 0xFFFF0000u);
      Wlo[off + i] = (unsigned short)(__float_as_uint(r) >> 16);
    }
  }
  if (tid < 512) {
    int k = tid >> 2, c = tid & 3;
    owT[c * 128 + k] = ow[k * 4 + c];
  }
}

// ---------------- SIREN forward v8: MFMA hi/lo split -------------------------
// Single wave per block, 32 points. LDS xl[p][k] fp32, 16 KB, XOR swizzle:
// logical 4-chunk kc of row p stored at physical kc ^ ((p&15)<<2).
// Hidden GEMM Y(128x32) = W^T * X via mfma_f32_16x16x32_bf16, 3-term split
// (xhi*whi + xhi*wlo + xlo*whi; dropped lo*lo ~2^-16 rel). 16 tiles (8 jt x
// 2 pt-sets), 64 f32 acc. W streams from prep-built fragment-ordered Whi/Wlo.
// First layer (K=3) and output layer (N=4) stay VALU.
#define INV2PI 0.15915494309189535f

__global__ __launch_bounds__(64, 2) void k_siren(const float *pts, const float *freqs,
                                                 const float *phases,
                                                 const float *fw, const float *fb,
                                                 const unsigned short *Whi,
                                                 const unsigned short *Wlo,
                                                 const float *hb,
                                                 const float *owT, const float *ob,
                                                 float *outp) {
  __shared__ __align__(16) float xl[32 * 128];   // [p][k], 16 KB
  const int lane = threadIdx.x;
  const int col = lane & 15;
  const int quad = lane >> 4;
  const int base = blockIdx.x * 32;
  const int b = base / PPB;
  const float *fqb = freqs + b * 768;
  const float *phb = phases + b * 768;

  // ---- first layer (VALU): lane = (col -> dims 8col..8col+7, quad -> pts 8quad..+7)
  {
    float pt[24];
    const float4 *ps = (const float4 *)(pts + (size_t)(base + 8 * quad) * 3);
#pragma unroll
    for (int i = 0; i < 6; i++) ((float4 *)pt)[i] = ps[i];
    float frv[8], prv[8], w0v[8], w1v[8], w2v[8], biv[8];
#pragma unroll
    for (int u = 0; u < 2; u++) {
      ((float4 *)frv)[u] = ((const float4 *)fqb)[2 * col + u];
      ((float4 *)prv)[u] = ((const float4 *)phb)[2 * col + u];
      ((float4 *)w0v)[u] = ((const float4 *)fw)[2 * col + u];
      ((float4 *)w1v)[u] = ((const float4 *)(fw + 128))[2 * col + u];
      ((float4 *)w2v)[u] = ((const float4 *)(fw + 256))[2 * col + u];
      ((float4 *)biv)[u] = ((const float4 *)fb)[2 * col + u];
    }
#pragma unroll
    for (int u = 0; u < 8; u++) { frv[u] *= INV2PI; prv[u] *= INV2PI; }
#pragma unroll
    for (int p = 0; p < 8; p++) {
      float x = pt[3 * p], y = pt[3 * p + 1], z = pt[3 * p + 2];
      float s[8];
#pragma unroll
      for (int j = 0; j < 8; j++)
        s[j] = __builtin_amdgcn_sinf(frv[j] * (x * w0v[j] + y * w1v[j] + z * w2v[j] + biv[j]) + prv[j]);
      int pp = 8 * quad + p;
      int s4 = (pp & 15) << 2;
      float4 v0, v1;
      v0.x = s[0]; v0.y = s[1]; v0.z = s[2]; v0.w = s[3];
      v1.x = s[4]; v1.y = s[5]; v1.z = s[6]; v1.w = s[7];
      *((float4 *)&xl[pp * 128 + ((8 * col) ^ s4)]) = v0;
      *((float4 *)&xl[pp * 128 + ((8 * col + 4) ^ s4)]) = v1;
    }
  }
  __syncthreads();

  // ---- hidden layers: MFMA ----
#pragma unroll 1
  for (int L = 1; L < 6; L++) {
    const int L1 = L - 1;
    f32x4 acc[2][8];
#pragma unroll
    for (int jt = 0; jt < 8; jt++) {
      const float4 bi = *((const float4 *)(hb + L1 * 128 + jt * 16 + quad * 4));
      f32x4 bv;
      bv[0] = bi.x; bv[1] = bi.y; bv[2] = bi.z; bv[3] = bi.w;
      acc[0][jt] = bv;
      acc[1][jt] = bv;
    }
    const short8 *WhiV = (const short8 *)Whi + (size_t)L1 * 32 * 64;
    const short8 *WloV = (const short8 *)Wlo + (size_t)L1 * 32 * 64;
#pragma unroll
    for (int kb = 0; kb < 4; kb++) {
      short8 bhi[2], blo[2];
#pragma unroll
      for (int s = 0; s < 2; s++) {
        int p = s * 16 + col;
        int s4 = col << 2;
        int jq = kb * 32 + quad * 8;
        const float4 x0 = *((const float4 *)&xl[p * 128 + (jq ^ s4)]);
        const float4 x1 = *((const float4 *)&xl[p * 128 + ((jq + 4) ^ s4)]);
        float v[8] = {x0.x, x0.y, x0.z, x0.w, x1.x, x1.y, x1.z, x1.w};
#pragma unroll
        for (int i = 0; i < 8; i++) {
          unsigned u = __float_as_uint(v[i]);
          bhi[s][i] = (short)(u >> 16);
          float r = v[i] - __uint_as_float(u & 0xFFFF0000u);
          blo[s][i] = (short)(__float_as_uint(r) >> 16);
        }
      }
#pragma unroll
      for (int jt = 0; jt < 8; jt++) {
        short8 ahi = WhiV[(jt * 4 + kb) * 64 + lane];
        short8 alo = WloV[(jt * 4 + kb) * 64 + lane];
        acc[0][jt] = __builtin_amdgcn_mfma_f32_16x16x32_bf16(ahi, bhi[0], acc[0][jt], 0, 0, 0);
        acc[0][jt] = __builtin_amdgcn_mfma_f32_16x16x32_bf16(ahi, blo[0], acc[0][jt], 0, 0, 0);
        acc[0][jt] = __builtin_amdgcn_mfma_f32_16x16x32_bf16(alo, bhi[0], acc[0][jt], 0, 0, 0);
        acc[1][jt] = __builtin_amdgcn_mfma_f32_16x16x32_bf16(ahi, bhi[1], acc[1][jt], 0, 0, 0);
        acc[1][jt] = __builtin_amdgcn_mfma_f32_16x16x32_bf16(ahi, blo[1], acc[1][jt], 0, 0, 0);
        acc[1][jt] = __builtin_amdgcn_mfma_f32_16x16x32_bf16(alo, bhi[1], acc[1][jt], 0, 0, 0);
      }
    }
    __syncthreads();
    // epilogue: lane holds rows j = jt*16 + quad*4 + reg, cols p = s*16 + col
#pragma unroll
    for (int jt = 0; jt < 8; jt++) {
      const float4 fq = *((const float4 *)(fqb + L * 128 + jt * 16 + quad * 4));
      const float4 ph = *((const float4 *)(phb + L * 128 + jt * 16 + quad * 4));
#pragma unroll
      for (int s = 0; s < 2; s++) {
        float4 v;
        v.x = __builtin_amdgcn_sinf(fq.x * INV2PI * acc[s][jt][0] + ph.x * INV2PI);
        v.y = __builtin_amdgcn_sinf(fq.y * INV2PI * acc[s][jt][1] + ph.y * INV2PI);
        v.z = __builtin_amdgcn_sinf(fq.z * INV2PI * acc[s][jt][2] + ph.z * INV2PI);
        v.w = __builtin_amdgcn_sinf(fq.w * INV2PI * acc[s][jt][3] + ph.w * INV2PI);
        int p = s * 16 + col;
        int s4 = col << 2;
        *((float4 *)&xl[p * 128 + ((jt * 16 + quad * 4) ^ s4)]) = v;
      }
    }
    __syncthreads();
  }

  // ---- output layer (VALU): lane -> (p = lane>>1, channel pair) -------------
  {
    int p = lane >> 1;
    int c2 = (lane & 1) * 2;
    int s4 = (p & 15) << 2;
    float a0 = ob[c2], a1 = ob[c2 + 1];
#pragma unroll 8
    for (int kk = 0; kk < 32; kk++) {
      const float4 xv = *((const float4 *)&xl[p * 128 + ((kk * 4) ^ s4)]);
      const float4 wA = *((const float4 *)(owT + c2 * 128 + kk * 4));
      const float4 wB = *((const float4 *)(owT + (c2 + 1) * 128 + kk * 4));
      a0 += xv.x * wA.x + xv.y * wA.y + xv.z * wA.z + xv.w * wA.w;
      a1 += xv.x * wB.x + xv.y * wB.y + xv.z * wB.z + xv.w * wB.w;
    }
    a0 = (c2 == 0) ? 1.0f / (1.0f + __expf(-a0)) : 1.0f / (1.0f + __expf(-a0));
    if (c2 == 0) a1 = 1.0f / (1.0f + __expf(-a1));
    float2 vv; vv.x = a0; vv.y = a1;
    *((float2 *)&outp[(size_t)(base + p) * 4 + c2]) = vv;
  }
}

// ---------------- coarse weights -> sample_pdf -> fine points ----------------
__global__ __launch_bounds__(256) void k_pdf(const float *zv, const float *coutb,
                                             const float *c2w, float *fz, float *fpts,
                                             unsigned kq0, unsigned kq1, int nrays) {
  int ray = blockIdx.x * 256 + threadIdx.x;
  if (ray >= nrays) return;
  int b = ray / HW, n = ray % HW;
  float z[12];
#pragma unroll
  for (int s = 0; s < 12; s++) z[s] = zv[ray * 12 + s];
  float w[12]; float T = 1.0f;
#pragma unroll
  for (int s = 0; s < 12; s++) {
    float d = (s < 11) ? z[s + 1] - z[s] : 1e10f;
    float sg = coutb[(ray * 12 + s) * 4 + 3];
    float a = 1.0f - expf(-d * fmaxf(sg, 0.0f));
    w[s] = a * T;
    T *= 1.0f - a + 1e-10f;
  }
  float zmid[11];
#pragma unroll
  for (int i = 0; i < 11; i++) zmid[i] = 0.5f * (z[i] + z[i + 1]);
  float pw[10], sum = 0.0f;
#pragma unroll
  for (int i = 0; i < 10; i++) { pw[i] = w[i + 1] + 1e-5f; sum += pw[i]; }
  float cdf[11]; cdf[0] = 0.0f; float cacc = 0.0f;
#pragma unroll
  for (int i = 0; i < 10; i++) { cacc += pw[i] / sum; cdf[i + 1] = cacc; }

  const float *M = c2w + b * 16;
  float m[12];
#pragma unroll
  for (int i = 0; i < 12; i++) m[i] = M[i];
  float dx, dy, dz; pixel_dir(n, dx, dy, dz);
  float tdx = m[0] * dx + m[1] * dy + m[2] * dz;
  float tdy = m[4] * dx + m[5] * dy + m[6] * dz;
  float tdz = m[8] * dx + m[9] * dy + m[10] * dz;
  float ox = m[3], oy = m[7], oz = m[11];

#pragma unroll
  for (int t = 0; t < 12; t++) {
    float u = jax_uniform(kq0, kq1, (unsigned)(ray * 12 + t), (unsigned)(nrays * 12));
    int ind = 0;
#pragma unroll
    for (int i = 0; i < 11; i++) ind += (cdf[i] <= u) ? 1 : 0;  // searchsorted 'right'
    int below = ind - 1; below = below < 0 ? 0 : (below > 10 ? 10 : below);
    int above = ind > 10 ? 10 : ind;
    float cl = 0.f, ch = 0.f, blo = 0.f, bhi = 0.f;
#pragma unroll
    for (int i = 0; i < 11; i++) {
      if (i == below) { cl = cdf[i]; blo = zmid[i]; }
      if (i == above) { ch = cdf[i]; bhi = zmid[i]; }
    }
    float den = ch - cl; if (den < 1e-8f) den = 1.0f;
    float f = blo + (u - cl) / den * (bhi - blo);
    fz[ray * 12 + t] = f;
    fpts[(ray * 12 + t) * 3 + 0] = ox + tdx * f;
    fpts[(ray * 12 + t) * 3 + 1] = oy + tdy * f;
    fpts[(ray * 12 + t) * 3 + 2] = oz + tdz * f;
  }
}

// ---------------- merge (stable sort by z), final integration ----------------
__global__ __launch_bounds__(64) void k_final(const float *zv, const float *fz,
                                              const float *coutb, const float *foutb,
                                              float *outp, int B) {
  __shared__ float L[120 * 64];   // per-thread column: z[24], sig[24], rgb[3][24]
  __shared__ int inv[24 * 64];
  int t = threadIdx.x;
  int ray = blockIdx.x * 64 + t;
  int b = ray / HW, n = ray % HW;
#define SL(e) L[(e) * 64 + t]
  float zr[24];
#pragma unroll
  for (int s = 0; s < 12; s++) {
    float zfv = fz[ray * 12 + s], zcv = zv[ray * 12 + s];
    zr[s] = zfv; zr[12 + s] = zcv;   // concat order: fine first, then coarse
    SL(s) = zfv; SL(12 + s) = zcv;
    SL(24 + s)      = foutb[(ray * 12 + s) * 4 + 3];
    SL(24 + 12 + s) = coutb[(ray * 12 + s) * 4 + 3];
#pragma unroll
    for (int c = 0; c < 3; c++) {
      SL(48 + c * 24 + s)      = foutb[(ray * 12 + s) * 4 + c];
      SL(48 + c * 24 + 12 + s) = coutb[(ray * 12 + s) * 4 + c];
    }
  }
  // stable ranks (ties broken by original index) == JAX stable argsort
#pragma unroll
  for (int i = 0; i < 24; i++) {
    int rank = 0;
#pragma unroll
    for (int j = 0; j < 24; j++)
      rank += (zr[j] < zr[i] || (zr[j] == zr[i] && j < i)) ? 1 : 0;
    inv[rank * 64 + t] = i;
  }
  float Tacc = 1.0f, r0 = 0.f, r1 = 0.f, r2 = 0.f, df = 0.f;
  int icur = inv[0 * 64 + t];
  float zcur = SL(icur);
  for (int r = 0; r < 24; r++) {
    int inext = 0; float znext = 0.f;
    if (r < 23) { inext = inv[(r + 1) * 64 + t]; znext = SL(inext); }
    float d = (r < 23) ? znext - zcur : 1e10f;
    float sg = SL(24 + icur);
    float a = 1.0f - expf(-d * fmaxf(sg, 0.0f));
    float wt = a * Tacc;
    Tacc *= 1.0f - a + 1e-10f;
    r0 += wt * SL(48 + icur);
    r1 += wt * SL(48 + 24 + icur);
    r2 += wt * SL(48 + 48 + icur);
    df += wt * zcur;
    icur = inext; zcur = znext;
  }
#undef SL
  int pi = n >> 6, pj = n & 63;
  float x = -1.0f + (float)pj * (2.0f / 63.0f);
  float y =  1.0f - (float)pi * (2.0f / 63.0f);
  float zc = -1.0f / tanf(0.10471975511965978f);
  float invn = 1.0f / sqrtf(x * x + y * y + zc * zc);
  float mdz = -zc * invn;  // -rays_d.z (positive)
  outp[(b * 3 + 0) * HW + n] = r0 * 2.0f - 1.0f;
  outp[(b * 3 + 1) * HW + n] = r1 * 2.0f - 1.0f;
  outp[(b * 3 + 2) * HW + n] = r2 * 2.0f - 1.0f;
  outp[B * 3 * HW + ray] = df * mdz;
}

extern "C" void kernel_launch(void *const *d_in, const int *in_sizes, int n_in,
                              void *d_out, int out_size, void *d_ws, size_t ws_size,
                              hipStream_t stream) {
  const float *z   = (const float *)d_in[0];
  const float *c2w = (const float *)d_in[1];
  const float *mw0 = (const float *)d_in[2];
  const float *mb0 = (const float *)d_in[3];
  const float *mw1 = (const float *)d_in[4];
  const float *mb1 = (const float *)d_in[5];
  const float *mw2 = (const float *)d_in[6];
  const float *mb2 = (const float *)d_in[7];
  const float *fw  = (const float *)d_in[8];
  const float *fb  = (const float *)d_in[9];
  const float *hw  = (const float *)d_in[10];
  const float *hb  = (const float *)d_in[11];
  const float *ow  = (const float *)d_in[12];
  const float *ob  = (const float *)d_in[13];
  int B = in_sizes[0] / 256;
  int npts = B * PPB;
  int nrays = B * HW;

  float *ws     = (float *)d_ws;
  float *freqs  = ws;
  float *phases = freqs + (size_t)B * 768;
  float *zv     = phases + (size_t)B * 768;
  float *cpts   = zv + npts;
  float *coutb  = cpts + (size_t)npts * 3;
  float *fzv    = coutb + (size_t)npts * 4;
  float *fpts   = fzv + npts;
  float *foutb  = fpts + (size_t)npts * 3;
  unsigned short *whi = (unsigned short *)(foutb + (size_t)npts * 4);  // 16B-aligned
  unsigned short *wlo = whi + 81920;    // 5*8*4*512
  float *owT = (float *)(wlo + 81920);

  // key(42) = [0,42]; split -> k_pert, k_pdf
  unsigned kp0, kp1, kq0, kq1;
#if JAX_PARTITIONABLE
  { unsigned o0, o1;
    tf2x32(0u, 42u, 0u, 0u, o0, o1); kp0 = o0; kp1 = o1;
    tf2x32(0u, 42u, 0u, 1u, o0, o1); kq0 = o0; kq1 = o1; }
#else
  { unsigned a0, a1, c0, c1;
    tf2x32(0u, 42u, 0u, 2u, a0, a1);
    tf2x32(0u, 42u, 1u, 3u, c0, c1);
    kp0 = a0; kp1 = c0; kq0 = a1; kq1 = c1; }
#endif

  k_prep<<<40, 256, 0, stream>>>(hw, ow, whi, wlo, owT);
  k_map<<<B, 256, 0, stream>>>(z, mw0, mb0, mw1, mb1, mw2, mb2, freqs, phases);
  k_rays<<<(npts + 255) / 256, 256, 0, stream>>>(c2w, zv, cpts, kp0, kp1, npts);
  k_siren<<<npts / 32, 64, 0, stream>>>(cpts, freqs, phases, fw, fb, whi, wlo, hb, owT, ob, coutb);
  k_pdf<<<(nrays + 255) / 256, 256, 0, stream>>>(zv, coutb, c2w, fzv, fpts, kq0, kq1, nrays);
  k_siren<<<npts / 32, 64, 0, stream>>>(fpts, freqs, phases, fw, fb, whi, wlo, hb, owT, ob, foutb);
  k_final<<<nrays / 64, 64, 0, stream>>>(zv, fzv, coutb, foutb, (float *)d_out, B);
}

// Round 11
// 290.461 us; speedup vs baseline: 3.8826x; 1.1773x over previous
//
#include <hip/hip_runtime.h>
#include <hip/hip_bf16.h>

// ---- JAX PRNG variant switches (verified passing in R2) ----
#define JAX_PARTITIONABLE 1
#define PART_MODE 2   // bits = o0 ^ o1

#define HW 4096      // 64*64 pixels
#define NS 12        // num_steps
#define PPB 49152    // HW*NS points per batch element

typedef __attribute__((ext_vector_type(8))) short short8;
typedef __attribute__((ext_vector_type(4))) float f32x4;

__host__ __device__ __forceinline__ void tf2x32(unsigned k0, unsigned k1,
                                                unsigned x0, unsigned x1,
                                                unsigned &o0, unsigned &o1) {
  unsigned ks2 = k0 ^ k1 ^ 0x1BD11BDAu;
  unsigned v0 = x0 + k0, v1 = x1 + k1;
#define TFR(r) do { v0 += v1; v1 = (v1 << (r)) | (v1 >> (32 - (r))); v1 ^= v0; } while (0)
  TFR(13); TFR(15); TFR(26); TFR(6);   v0 += k1;  v1 += ks2 + 1u;
  TFR(17); TFR(29); TFR(16); TFR(24);  v0 += ks2; v1 += k0 + 2u;
  TFR(13); TFR(15); TFR(26); TFR(6);   v0 += k0;  v1 += k1 + 3u;
  TFR(17); TFR(29); TFR(16); TFR(24);  v0 += k1;  v1 += ks2 + 4u;
  TFR(13); TFR(15); TFR(26); TFR(6);   v0 += ks2; v1 += k0 + 5u;
#undef TFR
  o0 = v0; o1 = v1;
}

__device__ __forceinline__ float jax_uniform(unsigned k0, unsigned k1,
                                             unsigned idx, unsigned total) {
  unsigned o0, o1, bits;
#if JAX_PARTITIONABLE
  tf2x32(k0, k1, 0u, idx, o0, o1);
#if PART_MODE == 0
  bits = o0;
#elif PART_MODE == 1
  bits = o1;
#else
  bits = o0 ^ o1;
#endif
#else
  unsigned half = total >> 1;
  if (idx < half) { tf2x32(k0, k1, idx, idx + half, o0, o1); bits = o0; }
  else            { tf2x32(k0, k1, idx - half, idx, o0, o1); bits = o1; }
#endif
  return __uint_as_float(0x3f800000u | (bits >> 9)) - 1.0f;
}

__device__ __forceinline__ void pixel_dir(int n, float &dx, float &dy, float &dz) {
  int pi = n >> 6, pj = n & 63;
  float x = -1.0f + (float)pj * (2.0f / 63.0f);
  float y =  1.0f - (float)pi * (2.0f / 63.0f);
  float zc = -1.0f / tanf(0.10471975511965978f);  // deg2rad(12)/2
  float inv = 1.0f / sqrtf(x * x + y * y + zc * zc);
  dx = x * inv; dy = y * inv; dz = zc * inv;
}

// ---------------- mapping network: z(256) -> freqs/phases (768 each) ---------
__global__ __launch_bounds__(256) void k_map(const float *z, const float *w0, const float *b0,
                                             const float *w1, const float *b1,
                                             const float *w2, const float *b2,
                                             float *freqs, float *phases) {
  __shared__ float zl[256], h1[256], h2[256];
  int b = blockIdx.x, t = threadIdx.x;
  zl[t] = z[b * 256 + t];
  __syncthreads();
  float acc = b0[t];
  for (int k = 0; k < 256; k++) acc += zl[k] * w0[k * 256 + t];
  h1[t] = (acc >= 0.0f) ? acc : 0.2f * acc;
  __syncthreads();
  acc = b1[t];
  for (int k = 0; k < 256; k++) acc += h1[k] * w1[k * 256 + t];
  h2[t] = (acc >= 0.0f) ? acc : 0.2f * acc;
  __syncthreads();
  float a6[6];
#pragma unroll
  for (int m = 0; m < 6; m++) a6[m] = b2[t + m * 256];
  for (int k = 0; k < 256; k++) {
    float h = h2[k];
#pragma unroll
    for (int m = 0; m < 6; m++) a6[m] += h * w2[k * 1536 + t + m * 256];
  }
#pragma unroll
  for (int m = 0; m < 6; m++) {
    int o = t + m * 256;
    if (o < 768) freqs[b * 768 + o] = a6[m] * 15.0f + 30.0f;
    else         phases[b * 768 + (o - 768)] = a6[m];
  }
}

// ---------------- coarse rays: perturbed z + transformed points --------------
__global__ __launch_bounds__(256) void k_rays(const float *c2w, float *zv, float *pts,
                                              unsigned kp0, unsigned kp1, int npts) {
  int e = blockIdx.x * 256 + threadIdx.x;
  if (e >= npts) return;
  int b = e / PPB, r = e % PPB, n = r / NS, s = r % NS;
  float dx, dy, dz; pixel_dir(n, dx, dy, dz);
  float delta = (1.12f - 0.88f) / 11.0f;
  float u = jax_uniform(kp0, kp1, (unsigned)e, (unsigned)npts);
  float zval = 0.88f + (float)s * delta + (u - 0.5f) * (float)(0.24 / 11.0);
  zv[e] = zval;
  float px = dx * zval, py = dy * zval, pz = dz * zval;
  const float *M = c2w + b * 16;
  float m[12];
#pragma unroll
  for (int i = 0; i < 12; i++) m[i] = M[i];
  pts[e * 3 + 0] = m[0] * px + m[1] * py + m[2] * pz + m[3];
  pts[e * 3 + 1] = m[4] * px + m[5] * py + m[6] * pz + m[7];
  pts[e * 3 + 2] = m[8] * px + m[9] * py + m[10] * pz + m[11];
}

// ---------------- weight prep: hi/lo bf16 split in MFMA A-fragment order -----
// A = hid_w^T per layer: A[j][k] = hw[L][k][j]. Fragment for mfma_16x16x32:
// lane holds A[m=lane&15][k = (lane>>4)*8 + i], i=0..7. Chunk = (L*8+jt)*4+kb.
// Truncation split: hi = topbits(w); lo = bf16(w - hi). Also owT[c][k] transpose.
__global__ __launch_bounds__(256) void k_prep(const float *hw, const float *ow,
                                              unsigned short *Whi, unsigned short *Wlo,
                                              float *owT) {
  int tid = blockIdx.x * 256 + threadIdx.x;
  if (tid < 10240) {
    int lane = tid & 63;
    int chunk = tid >> 6;          // (L*8+jt)*4+kb, L=0..4
    int kb = chunk & 3;
    int jt = (chunk >> 2) & 7;
    int L = chunk >> 5;
    int m = lane & 15, quad = lane >> 4;
    int j = jt * 16 + m;
    int k0 = kb * 32 + quad * 8;
    size_t off = (size_t)chunk * 512 + lane * 8;
#pragma unroll
    for (int i = 0; i < 8; i++) {
      float wv = hw[((size_t)L * 128 + k0 + i) * 128 + j];
      unsigned u = __float_as_uint(wv);
      Whi[off + i] = (unsigned short)(u >> 16);
      float r = wv - __uint_as_float(u & 0xFFFF0000u);
      Wlo[off + i] = (unsigned short)(__float_as_uint(r) >> 16);
    }
  }
  if (tid < 512) {
    int k = tid >> 2, c = tid & 3;
    owT[c * 128 + k] = ow[k * 4 + c];
  }
}

// ---------------- SIREN forward v9: MFMA + A-fragment prefetch ---------------
// Single wave/block, 32 points, 16 KB LDS (10 blocks/CU). R10 counters showed
// MfmaUtil 15.5 / VALU 18 — latency-bound on dependent L2 A-frag loads
// (~200 cyc before each 29-cyc MFMA burst). v9: 8 groups/layer (kb x half,
// 4 jt each), register double buffer: group G+1's 8 short8 loads issue before
// group G's 24 MFMAs + conversions (~150-350 cyc in flight > 200 cyc L2).
// Buffer = 64 VGPR; target total ~150 (<=168 keeps 10 blocks/CU).
// Numerics identical to R10 (same per-acc MFMA order).
#define INV2PI 0.15915494309189535f

__global__ __launch_bounds__(64, 2) void k_siren(const float *pts, const float *freqs,
                                                 const float *phases,
                                                 const float *fw, const float *fb,
                                                 const unsigned short *Whi,
                                                 const unsigned short *Wlo,
                                                 const float *hb,
                                                 const float *owT, const float *ob,
                                                 float *outp) {
  __shared__ __align__(16) float xl[32 * 128];   // [p][k], 16 KB
  const int lane = threadIdx.x;
  const int col = lane & 15;
  const int quad = lane >> 4;
  const int base = blockIdx.x * 32;
  const int b = base / PPB;
  const float *fqb = freqs + b * 768;
  const float *phb = phases + b * 768;

  // ---- first layer (VALU): lane = (col -> dims 8col..8col+7, quad -> pts 8quad..+7)
  {
    float pt[24];
    const float4 *ps = (const float4 *)(pts + (size_t)(base + 8 * quad) * 3);
#pragma unroll
    for (int i = 0; i < 6; i++) ((float4 *)pt)[i] = ps[i];
    float frv[8], prv[8], w0v[8], w1v[8], w2v[8], biv[8];
#pragma unroll
    for (int u = 0; u < 2; u++) {
      ((float4 *)frv)[u] = ((const float4 *)fqb)[2 * col + u];
      ((float4 *)prv)[u] = ((const float4 *)phb)[2 * col + u];
      ((float4 *)w0v)[u] = ((const float4 *)fw)[2 * col + u];
      ((float4 *)w1v)[u] = ((const float4 *)(fw + 128))[2 * col + u];
      ((float4 *)w2v)[u] = ((const float4 *)(fw + 256))[2 * col + u];
      ((float4 *)biv)[u] = ((const float4 *)fb)[2 * col + u];
    }
#pragma unroll
    for (int u = 0; u < 8; u++) { frv[u] *= INV2PI; prv[u] *= INV2PI; }
#pragma unroll
    for (int p = 0; p < 8; p++) {
      float x = pt[3 * p], y = pt[3 * p + 1], z = pt[3 * p + 2];
      float s[8];
#pragma unroll
      for (int j = 0; j < 8; j++)
        s[j] = __builtin_amdgcn_sinf(frv[j] * (x * w0v[j] + y * w1v[j] + z * w2v[j] + biv[j]) + prv[j]);
      int pp = 8 * quad + p;
      int s4 = (pp & 15) << 2;
      float4 v0, v1;
      v0.x = s[0]; v0.y = s[1]; v0.z = s[2]; v0.w = s[3];
      v1.x = s[4]; v1.y = s[5]; v1.z = s[6]; v1.w = s[7];
      *((float4 *)&xl[pp * 128 + ((8 * col) ^ s4)]) = v0;
      *((float4 *)&xl[pp * 128 + ((8 * col + 4) ^ s4)]) = v1;
    }
  }
  __syncthreads();

  // ---- hidden layers: MFMA with double-buffered A-frag prefetch ----
#pragma unroll 1
  for (int L = 1; L < 6; L++) {
    const int L1 = L - 1;
    f32x4 acc[2][8];
#pragma unroll
    for (int jt = 0; jt < 8; jt++) {
      const float4 bi = *((const float4 *)(hb + L1 * 128 + jt * 16 + quad * 4));
      f32x4 bv;
      bv[0] = bi.x; bv[1] = bi.y; bv[2] = bi.z; bv[3] = bi.w;
      acc[0][jt] = bv;
      acc[1][jt] = bv;
    }
    const short8 *WhiV = (const short8 *)Whi + (size_t)L1 * 2048;
    const short8 *WloV = (const short8 *)Wlo + (size_t)L1 * 2048;

    short8 bufh[2][4], bufl[2][4];
    // prefetch group 0 (kb=0, jts 0..3)
#pragma unroll
    for (int j = 0; j < 4; j++) {
      bufh[0][j] = WhiV[(j * 4 + 0) * 64 + lane];
      bufl[0][j] = WloV[(j * 4 + 0) * 64 + lane];
    }
    short8 xhi[2], xlo[2];
#pragma unroll
    for (int G = 0; G < 8; G++) {
      const int kb = G >> 1, half = G & 1;
      const int cur = G & 1, nxt = (G + 1) & 1;
      // issue next group's loads first (stay in flight across this group's work)
      if (G < 7) {
        const int nkb = (G + 1) >> 1, nh = (G + 1) & 1;
#pragma unroll
        for (int j = 0; j < 4; j++) {
          bufh[nxt][j] = WhiV[((nh * 4 + j) * 4 + nkb) * 64 + lane];
          bufl[nxt][j] = WloV[((nh * 4 + j) * 4 + nkb) * 64 + lane];
        }
      }
      // at each new kb: convert B fragments from LDS (overlaps the loads)
      if (half == 0) {
        const int jq = kb * 32 + quad * 8;
#pragma unroll
        for (int s = 0; s < 2; s++) {
          int p = s * 16 + col;
          int s4 = col << 2;
          const float4 x0 = *((const float4 *)&xl[p * 128 + (jq ^ s4)]);
          const float4 x1 = *((const float4 *)&xl[p * 128 + ((jq + 4) ^ s4)]);
          float v[8] = {x0.x, x0.y, x0.z, x0.w, x1.x, x1.y, x1.z, x1.w};
#pragma unroll
          for (int i = 0; i < 8; i++) {
            unsigned u = __float_as_uint(v[i]);
            xhi[s][i] = (short)(u >> 16);
            float r = v[i] - __uint_as_float(u & 0xFFFF0000u);
            xlo[s][i] = (short)(__float_as_uint(r) >> 16);
          }
        }
      }
      // MFMAs for jts half*4 .. half*4+3 (same per-acc order as R10)
#pragma unroll
      for (int j = 0; j < 4; j++) {
        const int jt = half * 4 + j;
        short8 ah = bufh[cur][j];
        short8 al = bufl[cur][j];
        acc[0][jt] = __builtin_amdgcn_mfma_f32_16x16x32_bf16(ah, xhi[0], acc[0][jt], 0, 0, 0);
        acc[1][jt] = __builtin_amdgcn_mfma_f32_16x16x32_bf16(ah, xhi[1], acc[1][jt], 0, 0, 0);
        acc[0][jt] = __builtin_amdgcn_mfma_f32_16x16x32_bf16(ah, xlo[0], acc[0][jt], 0, 0, 0);
        acc[1][jt] = __builtin_amdgcn_mfma_f32_16x16x32_bf16(ah, xlo[1], acc[1][jt], 0, 0, 0);
        acc[0][jt] = __builtin_amdgcn_mfma_f32_16x16x32_bf16(al, xhi[0], acc[0][jt], 0, 0, 0);
        acc[1][jt] = __builtin_amdgcn_mfma_f32_16x16x32_bf16(al, xhi[1], acc[1][jt], 0, 0, 0);
      }
    }
    __syncthreads();
    // epilogue: lane holds rows j = jt*16 + quad*4 + reg, cols p = s*16 + col
#pragma unroll
    for (int jt = 0; jt < 8; jt++) {
      const float4 fq = *((const float4 *)(fqb + L * 128 + jt * 16 + quad * 4));
      const float4 ph = *((const float4 *)(phb + L * 128 + jt * 16 + quad * 4));
#pragma unroll
      for (int s = 0; s < 2; s++) {
        float4 v;
        v.x = __builtin_amdgcn_sinf(fq.x * INV2PI * acc[s][jt][0] + ph.x * INV2PI);
        v.y = __builtin_amdgcn_sinf(fq.y * INV2PI * acc[s][jt][1] + ph.y * INV2PI);
        v.z = __builtin_amdgcn_sinf(fq.z * INV2PI * acc[s][jt][2] + ph.z * INV2PI);
        v.w = __builtin_amdgcn_sinf(fq.w * INV2PI * acc[s][jt][3] + ph.w * INV2PI);
        int p = s * 16 + col;
        int s4 = col << 2;
        *((float4 *)&xl[p * 128 + ((jt * 16 + quad * 4) ^ s4)]) = v;
      }
    }
    __syncthreads();
  }

  // ---- output layer (VALU): lane -> (p = lane>>1, channel pair) -------------
  {
    int p = lane >> 1;
    int c2 = (lane & 1) * 2;
    int s4 = (p & 15) << 2;
    float a0 = ob[c2], a1 = ob[c2 + 1];
#pragma unroll 8
    for (int kk = 0; kk < 32; kk++) {
      const float4 xv = *((const float4 *)&xl[p * 128 + ((kk * 4) ^ s4)]);
      const float4 wA = *((const float4 *)(owT + c2 * 128 + kk * 4));
      const float4 wB = *((const float4 *)(owT + (c2 + 1) * 128 + kk * 4));
      a0 += xv.x * wA.x + xv.y * wA.y + xv.z * wA.z + xv.w * wA.w;
      a1 += xv.x * wB.x + xv.y * wB.y + xv.z * wB.z + xv.w * wB.w;
    }
    a0 = 1.0f / (1.0f + __expf(-a0));
    if (c2 == 0) a1 = 1.0f / (1.0f + __expf(-a1));
    float2 vv; vv.x = a0; vv.y = a1;
    *((float2 *)&outp[(size_t)(base + p) * 4 + c2]) = vv;
  }
}

// ---------------- coarse weights -> sample_pdf -> fine points ----------------
__global__ __launch_bounds__(256) void k_pdf(const float *zv, const float *coutb,
                                             const float *c2w, float *fz, float *fpts,
                                             unsigned kq0, unsigned kq1, int nrays) {
  int ray = blockIdx.x * 256 + threadIdx.x;
  if (ray >= nrays) return;
  int b = ray / HW, n = ray % HW;
  float z[12];
#pragma unroll
  for (int s = 0; s < 12; s++) z[s] = zv[ray * 12 + s];
  float w[12]; float T = 1.0f;
#pragma unroll
  for (int s = 0; s < 12; s++) {
    float d = (s < 11) ? z[s + 1] - z[s] : 1e10f;
    float sg = coutb[(ray * 12 + s) * 4 + 3];
    float a = 1.0f - expf(-d * fmaxf(sg, 0.0f));
    w[s] = a * T;
    T *= 1.0f - a + 1e-10f;
  }
  float zmid[11];
#pragma unroll
  for (int i = 0; i < 11; i++) zmid[i] = 0.5f * (z[i] + z[i + 1]);
  float pw[10], sum = 0.0f;
#pragma unroll
  for (int i = 0; i < 10; i++) { pw[i] = w[i + 1] + 1e-5f; sum += pw[i]; }
  float cdf[11]; cdf[0] = 0.0f; float cacc = 0.0f;
#pragma unroll
  for (int i = 0; i < 10; i++) { cacc += pw[i] / sum; cdf[i + 1] = cacc; }

  const float *M = c2w + b * 16;
  float m[12];
#pragma unroll
  for (int i = 0; i < 12; i++) m[i] = M[i];
  float dx, dy, dz; pixel_dir(n, dx, dy, dz);
  float tdx = m[0] * dx + m[1] * dy + m[2] * dz;
  float tdy = m[4] * dx + m[5] * dy + m[6] * dz;
  float tdz = m[8] * dx + m[9] * dy + m[10] * dz;
  float ox = m[3], oy = m[7], oz = m[11];

#pragma unroll
  for (int t = 0; t < 12; t++) {
    float u = jax_uniform(kq0, kq1, (unsigned)(ray * 12 + t), (unsigned)(nrays * 12));
    int ind = 0;
#pragma unroll
    for (int i = 0; i < 11; i++) ind += (cdf[i] <= u) ? 1 : 0;  // searchsorted 'right'
    int below = ind - 1; below = below < 0 ? 0 : (below > 10 ? 10 : below);
    int above = ind > 10 ? 10 : ind;
    float cl = 0.f, ch = 0.f, blo = 0.f, bhi = 0.f;
#pragma unroll
    for (int i = 0; i < 11; i++) {
      if (i == below) { cl = cdf[i]; blo = zmid[i]; }
      if (i == above) { ch = cdf[i]; bhi = zmid[i]; }
    }
    float den = ch - cl; if (den < 1e-8f) den = 1.0f;
    float f = blo + (u - cl) / den * (bhi - blo);
    fz[ray * 12 + t] = f;
    fpts[(ray * 12 + t) * 3 + 0] = ox + tdx * f;
    fpts[(ray * 12 + t) * 3 + 1] = oy + tdy * f;
    fpts[(ray * 12 + t) * 3 + 2] = oz + tdz * f;
  }
}

// ---------------- merge (stable sort by z), final integration ----------------
__global__ __launch_bounds__(64) void k_final(const float *zv, const float *fz,
                                              const float *coutb, const float *foutb,
                                              float *outp, int B) {
  __shared__ float L[120 * 64];   // per-thread column: z[24], sig[24], rgb[3][24]
  __shared__ int inv[24 * 64];
  int t = threadIdx.x;
  int ray = blockIdx.x * 64 + t;
  int b = ray / HW, n = ray % HW;
#define SL(e) L[(e) * 64 + t]
  float zr[24];
#pragma unroll
  for (int s = 0; s < 12; s++) {
    float zfv = fz[ray * 12 + s], zcv = zv[ray * 12 + s];
    zr[s] = zfv; zr[12 + s] = zcv;   // concat order: fine first, then coarse
    SL(s) = zfv; SL(12 + s) = zcv;
    SL(24 + s)      = foutb[(ray * 12 + s) * 4 + 3];
    SL(24 + 12 + s) = coutb[(ray * 12 + s) * 4 + 3];
#pragma unroll
    for (int c = 0; c < 3; c++) {
      SL(48 + c * 24 + s)      = foutb[(ray * 12 + s) * 4 + c];
      SL(48 + c * 24 + 12 + s) = coutb[(ray * 12 + s) * 4 + c];
    }
  }
  // stable ranks (ties broken by original index) == JAX stable argsort
#pragma unroll
  for (int i = 0; i < 24; i++) {
    int rank = 0;
#pragma unroll
    for (int j = 0; j < 24; j++)
      rank += (zr[j] < zr[i] || (zr[j] == zr[i] && j < i)) ? 1 : 0;
    inv[rank * 64 + t] = i;
  }
  float Tacc = 1.0f, r0 = 0.f, r1 = 0.f, r2 = 0.f, df = 0.f;
  int icur = inv[0 * 64 + t];
  float zcur = SL(icur);
  for (int r = 0; r < 24; r++) {
    int inext = 0; float znext = 0.f;
    if (r < 23) { inext = inv[(r + 1) * 64 + t]; znext = SL(inext); }
    float d = (r < 23) ? znext - zcur : 1e10f;
    float sg = SL(24 + icur);
    float a = 1.0f - expf(-d * fmaxf(sg, 0.0f));
    float wt = a * Tacc;
    Tacc *= 1.0f - a + 1e-10f;
    r0 += wt * SL(48 + icur);
    r1 += wt * SL(48 + 24 + icur);
    r2 += wt * SL(48 + 48 + icur);
    df += wt * zcur;
    icur = inext; zcur = znext;
  }
#undef SL
  int pi = n >> 6, pj = n & 63;
  float x = -1.0f + (float)pj * (2.0f / 63.0f);
  float y =  1.0f - (float)pi * (2.0f / 63.0f);
  float zc = -1.0f / tanf(0.10471975511965978f);
  float invn = 1.0f / sqrtf(x * x + y * y + zc * zc);
  float mdz = -zc * invn;  // -rays_d.z (positive)
  outp[(b * 3 + 0) * HW + n] = r0 * 2.0f - 1.0f;
  outp[(b * 3 + 1) * HW + n] = r1 * 2.0f - 1.0f;
  outp[(b * 3 + 2) * HW + n] = r2 * 2.0f - 1.0f;
  outp[B * 3 * HW + ray] = df * mdz;
}

extern "C" void kernel_launch(void *const *d_in, const int *in_sizes, int n_in,
                              void *d_out, int out_size, void *d_ws, size_t ws_size,
                              hipStream_t stream) {
  const float *z   = (const float *)d_in[0];
  const float *c2w = (const float *)d_in[1];
  const float *mw0 = (const float *)d_in[2];
  const float *mb0 = (const float *)d_in[3];
  const float *mw1 = (const float *)d_in[4];
  const float *mb1 = (const float *)d_in[5];
  const float *mw2 = (const float *)d_in[6];
  const float *mb2 = (const float *)d_in[7];
  const float *fw  = (const float *)d_in[8];
  const float *fb  = (const float *)d_in[9];
  const float *hw  = (const float *)d_in[10];
  const float *hb  = (const float *)d_in[11];
  const float *ow  = (const float *)d_in[12];
  const float *ob  = (const float *)d_in[13];
  int B = in_sizes[0] / 256;
  int npts = B * PPB;
  int nrays = B * HW;

  float *ws     = (float *)d_ws;
  float *freqs  = ws;
  float *phases = freqs + (size_t)B * 768;
  float *zv     = phases + (size_t)B * 768;
  float *cpts   = zv + npts;
  float *coutb  = cpts + (size_t)npts * 3;
  float *fzv    = coutb + (size_t)npts * 4;
  float *fpts   = fzv + npts;
  float *foutb  = fpts + (size_t)npts * 3;
  unsigned short *whi = (unsigned short *)(foutb + (size_t)npts * 4);  // 16B-aligned
  unsigned short *wlo = whi + 81920;    // 5*8*4*512
  float *owT = (float *)(wlo + 81920);

  // key(42) = [0,42]; split -> k_pert, k_pdf
  unsigned kp0, kp1, kq0, kq1;
#if JAX_PARTITIONABLE
  { unsigned o0, o1;
    tf2x32(0u, 42u, 0u, 0u, o0, o1); kp0 = o0; kp1 = o1;
    tf2x32(0u, 42u, 0u, 1u, o0, o1); kq0 = o0; kq1 = o1; }
#else
  { unsigned a0, a1, c0, c1;
    tf2x32(0u, 42u, 0u, 2u, a0, a1);
    tf2x32(0u, 42u, 1u, 3u, c0, c1);
    kp0 = a0; kp1 = c0; kq0 = a1; kq1 = c1; }
#endif

  k_prep<<<40, 256, 0, stream>>>(hw, ow, whi, wlo, owT);
  k_map<<<B, 256, 0, stream>>>(z, mw0, mb0, mw1, mb1, mw2, mb2, freqs, phases);
  k_rays<<<(npts + 255) / 256, 256, 0, stream>>>(c2w, zv, cpts, kp0, kp1, npts);
  k_siren<<<npts / 32, 64, 0, stream>>>(cpts, freqs, phases, fw, fb, whi, wlo, hb, owT, ob, coutb);
  k_pdf<<<(nrays + 255) / 256, 256, 0, stream>>>(zv, coutb, c2w, fzv, fpts, kq0, kq1, nrays);
  k_siren<<<npts / 32, 64, 0, stream>>>(fpts, freqs, phases, fw, fb, whi, wlo, hb, owT, ob, foutb);
  k_final<<<nrays / 64, 64, 0, stream>>>(zv, fzv, coutb, foutb, (float *)d_out, B);
}